// Round 19
// baseline (126.856 us; speedup 1.0000x reference)
//
#include <hip/hip_runtime.h>
#include <hip/hip_bf16.h>
#include <cstdint>
#include <cstddef>

typedef __attribute__((ext_vector_type(4))) float f32x4;
typedef __attribute__((ext_vector_type(8))) short bf16x8;
typedef __attribute__((ext_vector_type(8))) unsigned short us8;

#define MFMA16(a, b, c) __builtin_amdgcn_mfma_f32_16x16x32_bf16(a, b, c, 0, 0, 0)

__device__ inline unsigned short f2bf(float f) {
    unsigned int u = __float_as_uint(f);
    u += 0x7fffu + ((u >> 16) & 1u);
    return (unsigned short)(u >> 16);
}
__device__ inline float bf2f(unsigned short u) {
    return __uint_as_float((unsigned int)u << 16);
}
__device__ inline unsigned short f2bf_fast(float f) {
    float r;
    asm("v_cvt_pk_bf16_f32 %0, %1, %2" : "=v"(r) : "v"(f), "v"(f));
    return (unsigned short)__float_as_uint(r);
}

__device__ inline void gload_lds16(const void* g, void* l) {
    __builtin_amdgcn_global_load_lds(
        (const __attribute__((address_space(1))) void*)g,
        (__attribute__((address_space(3))) void*)l, 16, 0, 0);
}
__device__ inline unsigned lds_addr(const void* p) {
    return (unsigned)(size_t)((__attribute__((address_space(3))) const void*)p);
}

// ---------------------------------------------------------------- fused prep: 5 f32->bf16 converts + RoPE table
__global__ __launch_bounds__(256) void prep_all(const float* __restrict__ x,
                                                const float* __restrict__ wq,
                                                const float* __restrict__ wk,
                                                const float* __restrict__ wv,
                                                const float* __restrict__ wo,
                                                unsigned short* __restrict__ xb,
                                                unsigned short* __restrict__ wqkv,
                                                unsigned short* __restrict__ wob,
                                                float2* __restrict__ tbl) {
    const int b = blockIdx.x;
    if (b < 14336) {
        const float* src; unsigned short* dst; int off4;
        if (b < 4096)       { src = x;  dst = xb;                 off4 = b; }
        else if (b < 8192)  { src = wq; dst = wqkv;               off4 = b - 4096; }
        else if (b < 9216)  { src = wk; dst = wqkv + 2048 * 2048; off4 = b - 8192; }
        else if (b < 10240) { src = wv; dst = wqkv + 2560 * 2048; off4 = b - 9216; }
        else                { src = wo; dst = wob;                off4 = b - 10240; }
        int i = (off4 * 256 + threadIdx.x) * 4;
        float4 v = *(const float4*)(src + i);
        ushort4 o;
        o.x = f2bf(v.x); o.y = f2bf(v.y); o.z = f2bf(v.z); o.w = f2bf(v.w);
        *(ushort4*)(dst + i) = o;
    } else {
        int idx = (b - 14336) * 256 + threadIdx.x;
        int row = idx >> 6, t = idx & 63;
        float inv_freq = exp2f((float)t * (-2.0f / 128.0f) * 13.287712379549449f);
        float s, c;
        sincosf((float)row * inv_freq, &s, &c);
        tbl[idx] = make_float2(c, s);
    }
}

// ---------------------------------------------------------------- gemm_qkv128: 128x256 tile, BK=64, fused RMSNorm+RoPE epilogue
// A=xb[2048][2048], B=wqkv[3072][2048]; bn owns heads {2bn, 2bn+1}
__global__ __launch_bounds__(512, 1) void gemm_qkv128(const unsigned short* __restrict__ A,
                                                      const unsigned short* __restrict__ B,
                                                      const float* __restrict__ qw,
                                                      const float* __restrict__ kw,
                                                      const float2* __restrict__ tbl,
                                                      unsigned short* __restrict__ Qb,
                                                      unsigned short* __restrict__ Kb,
                                                      unsigned short* __restrict__ Vb) {
    constexpr int K = 2048;
    constexpr int nK = K >> 6;                      // 32
    __shared__ __align__(16) char sm[98304];        // union: As[2][8192]+Bs[2][16384] | ybuf+ssbuf
    unsigned short* AsB = (unsigned short*)sm;      // [2][8192] shorts (16KB/buf)
    unsigned short* BsB = AsB + 16384;              // [2][16384] shorts (32KB/buf)
    const int tid = threadIdx.x;
    const int lane = tid & 63, wave = tid >> 6;
    const int wr = wave >> 2, wc = wave & 3;
    const int l15 = lane & 15, l4 = lane >> 4;
    const int gx = gridDim.x;                       // 12
    const int nwg = gx * gridDim.y;
    const int bid0 = blockIdx.y * gx + blockIdx.x;
    const int q8 = nwg >> 3, r8 = nwg & 7;
    const int xcd = bid0 & 7, sub = bid0 >> 3;
    const int wgid = ((xcd < r8) ? xcd * (q8 + 1) : r8 * (q8 + 1) + (xcd - r8) * q8) + sub;
    const int bm = wgid / gx, bn = wgid % gx;

    f32x4 acc[4][4] = {};

    const int sa0 = tid, sa1 = 512 + tid;
    const int sb2 = 1024 + tid, sb3 = 1536 + tid;
#define SRCOF(s) ((((((s) & 7) * 16) ^ ((((s) >> 3) & 7) << 4)) >> 1))
    const unsigned short* pa0 = A + (size_t)(bm * 128 + (sa0 >> 3)) * K + SRCOF(sa0);
    const unsigned short* pa1 = A + (size_t)(bm * 128 + (sa1 >> 3)) * K + SRCOF(sa1);
    const unsigned short* pb0 = B + (size_t)(bn * 256 + (sa0 >> 3)) * K + SRCOF(sa0);
    const unsigned short* pb1 = B + (size_t)(bn * 256 + (sa1 >> 3)) * K + SRCOF(sa1);
    const unsigned short* pb2 = B + (size_t)(bn * 256 + (sb2 >> 3)) * K + SRCOF(sb2);
    const unsigned short* pb3 = B + (size_t)(bn * 256 + (sb3 >> 3)) * K + SRCOF(sb3);
#undef SRCOF

#define STG(kt, bb)                                              \
    do {                                                         \
        gload_lds16(pa0 + (kt) * 64, AsB + (bb) * 8192 + sa0 * 8);  \
        gload_lds16(pa1 + (kt) * 64, AsB + (bb) * 8192 + sa1 * 8);  \
        gload_lds16(pb0 + (kt) * 64, BsB + (bb) * 16384 + sa0 * 8); \
        gload_lds16(pb1 + (kt) * 64, BsB + (bb) * 16384 + sa1 * 8); \
        gload_lds16(pb2 + (kt) * 64, BsB + (bb) * 16384 + sb2 * 8); \
        gload_lds16(pb3 + (kt) * 64, BsB + (bb) * 16384 + sb3 * 8); \
    } while (0)

    const unsigned swz = (unsigned)((l4 * 16) ^ ((l15 & 7) << 4));
    const unsigned aB0 = lds_addr(AsB) + (unsigned)((wr * 64 + l15) * 128) + swz;
    const unsigned bB0 = lds_addr(BsB) + (unsigned)((wc * 64 + l15) * 128) + swz;

#define DSR(dst, addr, off) \
    asm volatile("ds_read_b128 %0, %1 offset:" #off : "=v"(dst) : "v"(addr))

    STG(0, 0);
    for (int kt = 0; kt < nK; ++kt) {
        const int bc = kt & 1;
        asm volatile("s_waitcnt vmcnt(0)\ns_barrier" ::: "memory");
        __builtin_amdgcn_sched_barrier(0);

        const unsigned aA0 = aB0 + bc * 16384, aA1 = aA0 ^ 64u;
        const unsigned bA0 = bB0 + bc * 32768, bA1 = bA0 ^ 64u;
        bf16x8 a00, a01, a02, a03, a10, a11, a12, a13;
        bf16x8 b00, b01, b02, b03, b10, b11, b12, b13;

        // group1 (ks0): B 4 + A 4
        DSR(b00, bA0, 0);    DSR(b01, bA0, 2048);
        DSR(b02, bA0, 4096); DSR(b03, bA0, 6144);
        DSR(a00, aA0, 0);    DSR(a01, aA0, 2048);
        DSR(a02, aA0, 4096); DSR(a03, aA0, 6144);
        // group2 (ks1): B 4 + A 4
        DSR(b10, bA1, 0);    DSR(b11, bA1, 2048);
        DSR(b12, bA1, 4096); DSR(b13, bA1, 6144);
        DSR(a10, aA1, 0);    DSR(a11, aA1, 2048);
        DSR(a12, aA1, 4096); DSR(a13, aA1, 6144);

        if (kt + 1 < nK) STG(kt + 1, bc ^ 1);

        asm volatile("s_waitcnt lgkmcnt(8)" ::: "memory");   // group1 landed
        __builtin_amdgcn_sched_barrier(0);
        __builtin_amdgcn_s_setprio(1);
        acc[0][0] = MFMA16(a00, b00, acc[0][0]); acc[0][1] = MFMA16(a00, b01, acc[0][1]);
        acc[0][2] = MFMA16(a00, b02, acc[0][2]); acc[0][3] = MFMA16(a00, b03, acc[0][3]);
        acc[1][0] = MFMA16(a01, b00, acc[1][0]); acc[1][1] = MFMA16(a01, b01, acc[1][1]);
        acc[1][2] = MFMA16(a01, b02, acc[1][2]); acc[1][3] = MFMA16(a01, b03, acc[1][3]);
        acc[2][0] = MFMA16(a02, b00, acc[2][0]); acc[2][1] = MFMA16(a02, b01, acc[2][1]);
        acc[2][2] = MFMA16(a02, b02, acc[2][2]); acc[2][3] = MFMA16(a02, b03, acc[2][3]);
        acc[3][0] = MFMA16(a03, b00, acc[3][0]); acc[3][1] = MFMA16(a03, b01, acc[3][1]);
        acc[3][2] = MFMA16(a03, b02, acc[3][2]); acc[3][3] = MFMA16(a03, b03, acc[3][3]);
        __builtin_amdgcn_s_setprio(0);

        asm volatile("s_waitcnt lgkmcnt(0)" ::: "memory");   // group2 landed under group1 MFMA
        __builtin_amdgcn_sched_barrier(0);
        __builtin_amdgcn_s_setprio(1);
        acc[0][0] = MFMA16(a10, b10, acc[0][0]); acc[0][1] = MFMA16(a10, b11, acc[0][1]);
        acc[0][2] = MFMA16(a10, b12, acc[0][2]); acc[0][3] = MFMA16(a10, b13, acc[0][3]);
        acc[1][0] = MFMA16(a11, b10, acc[1][0]); acc[1][1] = MFMA16(a11, b11, acc[1][1]);
        acc[1][2] = MFMA16(a11, b12, acc[1][2]); acc[1][3] = MFMA16(a11, b13, acc[1][3]);
        acc[2][0] = MFMA16(a12, b10, acc[2][0]); acc[2][1] = MFMA16(a12, b11, acc[2][1]);
        acc[2][2] = MFMA16(a12, b12, acc[2][2]); acc[2][3] = MFMA16(a12, b13, acc[2][3]);
        acc[3][0] = MFMA16(a13, b10, acc[3][0]); acc[3][1] = MFMA16(a13, b11, acc[3][1]);
        acc[3][2] = MFMA16(a13, b12, acc[3][2]); acc[3][3] = MFMA16(a13, b13, acc[3][3]);
        __builtin_amdgcn_s_setprio(0);
    }
#undef STG
#undef DSR

    // ---------------- fused epilogue (2 heads per block; R5-validated) ----------------
    const int hl = wc >> 1;                 // head-local 0/1
    const int half = wc & 1;                // 0: cols 0..63, 1: cols 64..127 of the head
    __syncthreads();                        // LDS reads done; union region reusable

    if (bn >= 10) {                         // both heads are V (20..23)
        const int head_v = 2 * bn - 20 + hl;
        unsigned short* dst = Vb + (size_t)head_v * 2048 * 128;
        for (int m = 0; m < 4; ++m)
            for (int j = 0; j < 4; ++j) {
                int row = bm * 128 + wr * 64 + m * 16 + l4 * 4 + j;
                for (int n = 0; n < 4; ++n)
                    dst[(size_t)row * 128 + half * 64 + n * 16 + l15] = f2bf_fast(acc[m][n][j]);
            }
        return;
    }

    unsigned short* ybuf = (unsigned short*)sm;     // [128][264] bf16
    float* ssbuf = (float*)(sm + 67584);            // [4][128]
    for (int m = 0; m < 4; ++m)
        for (int j = 0; j < 4; ++j) {
            float ss = 0.0f;
            for (int n = 0; n < 4; ++n) ss += acc[m][n][j] * acc[m][n][j];
            for (int mk = 8; mk; mk >>= 1) ss += __shfl_xor(ss, mk);
            if (l15 == 0) ssbuf[wc * 128 + wr * 64 + m * 16 + l4 * 4 + j] = ss;
        }
    __syncthreads();
    const float* w = (bn < 8) ? qw : kw;
    float wv4[4];
    for (int n = 0; n < 4; ++n) wv4[n] = w[half * 64 + n * 16 + l15];
    for (int m = 0; m < 4; ++m)
        for (int j = 0; j < 4; ++j) {
            int lrow = wr * 64 + m * 16 + l4 * 4 + j;
            float tot = ssbuf[hl * 256 + lrow] + ssbuf[hl * 256 + 128 + lrow];
            float rr = rsqrtf(tot * (1.0f / 128.0f) + 1e-6f);
            for (int n = 0; n < 4; ++n)
                ybuf[lrow * 264 + wc * 64 + n * 16 + l15] = f2bf(acc[m][n][j] * rr * wv4[n]);
        }
    __syncthreads();
    const int head_g = 2 * bn + hl;
    unsigned short* dstbase = (bn < 8) ? Qb + (size_t)head_g * 2048 * 128
                                       : Kb + (size_t)(head_g - 16) * 2048 * 128;
    const float SCALE2 = 0.12751879526654698f;      // softmax scale * log2(e), folded into Q
    for (int m = 0; m < 4; ++m)
        for (int j = 0; j < 4; ++j) {
            int lrow = wr * 64 + m * 16 + l4 * 4 + j;
            int grow = bm * 128 + lrow;
            for (int n = 0; n < 4; ++n) {
                int wcol = wc * 64 + n * 16 + l15;        // 0..255
                float2 cs = tbl[grow * 64 + (wcol & 63)];
                float own = bf2f(ybuf[lrow * 264 + wcol]);
                float par = bf2f(ybuf[lrow * 264 + (wcol ^ 64)]);
                float outv = (half == 0) ? own * cs.x - par * cs.y
                                         : par * cs.y + own * cs.x;
                if (bn < 8) outv *= SCALE2;
                dstbase[(size_t)grow * 128 + (wcol & 127)] = f2bf(outv);
            }
        }
}

// ---------------------------------------------------------------- gemm256 (R16 proven): BK=64, 2-buffer, 4 counted-lgkm phases
__global__ __launch_bounds__(512, 1) void gemm256(const unsigned short* __restrict__ A,
                                                  const unsigned short* __restrict__ B,
                                                  unsigned short* __restrict__ Cp,
                                                  int M, int N, int Kfull, int kspan) {
    __shared__ unsigned short As[2][16384];
    __shared__ unsigned short Bs[2][16384];
    const int tid = threadIdx.x;
    const int lane = tid & 63, wave = tid >> 6;
    const int wr = wave >> 2, wc = wave & 3;
    const int l15 = lane & 15, l4 = lane >> 4;
    const int gx = gridDim.x;
    const int nwg = gx * gridDim.y;
    const int bid0 = blockIdx.y * gx + blockIdx.x;
    const int q8 = nwg >> 3, r8 = nwg & 7;
    const int xcd = bid0 & 7, sub = bid0 >> 3;
    const int wgid = ((xcd < r8) ? xcd * (q8 + 1) : r8 * (q8 + 1) + (xcd - r8) * q8) + sub;
    const int bm = wgid / gx, bn = wgid % gx;
    const int z = blockIdx.z;
    const unsigned short* Az = A + (size_t)z * kspan;
    const unsigned short* Bz = B + (size_t)z * kspan;
    unsigned short* C = Cp + (size_t)z * M * N;
    const int nK = kspan >> 6;

    f32x4 acc[8][4] = {};

    const int sA0 = tid, sA1 = 512 + tid, sA2 = 1024 + tid, sA3 = 1536 + tid;
#define SRCOF(s) ((((((s) & 7) * 16) ^ ((((s) >> 3) & 7) << 4)) >> 1))
    const unsigned short* pa0 = Az + (size_t)(bm * 256 + (sA0 >> 3)) * Kfull + SRCOF(sA0);
    const unsigned short* pa1 = Az + (size_t)(bm * 256 + (sA1 >> 3)) * Kfull + SRCOF(sA1);
    const unsigned short* pa2 = Az + (size_t)(bm * 256 + (sA2 >> 3)) * Kfull + SRCOF(sA2);
    const unsigned short* pa3 = Az + (size_t)(bm * 256 + (sA3 >> 3)) * Kfull + SRCOF(sA3);
    const unsigned short* pb0 = Bz + (size_t)(bn * 256 + (sA0 >> 3)) * Kfull + SRCOF(sA0);
    const unsigned short* pb1 = Bz + (size_t)(bn * 256 + (sA1 >> 3)) * Kfull + SRCOF(sA1);
    const unsigned short* pb2 = Bz + (size_t)(bn * 256 + (sA2 >> 3)) * Kfull + SRCOF(sA2);
    const unsigned short* pb3 = Bz + (size_t)(bn * 256 + (sA3 >> 3)) * Kfull + SRCOF(sA3);
#undef SRCOF

#define STG(kt, bb)                                            \
    do {                                                       \
        gload_lds16(pa0 + (kt) * 64, &As[bb][sA0 * 8]);        \
        gload_lds16(pa1 + (kt) * 64, &As[bb][sA1 * 8]);        \
        gload_lds16(pa2 + (kt) * 64, &As[bb][sA2 * 8]);        \
        gload_lds16(pa3 + (kt) * 64, &As[bb][sA3 * 8]);        \
        gload_lds16(pb0 + (kt) * 64, &Bs[bb][sA0 * 8]);        \
        gload_lds16(pb1 + (kt) * 64, &Bs[bb][sA1 * 8]);        \
        gload_lds16(pb2 + (kt) * 64, &Bs[bb][sA2 * 8]);        \
        gload_lds16(pb3 + (kt) * 64, &Bs[bb][sA3 * 8]);        \
    } while (0)

    const unsigned swz = (unsigned)((l4 * 16) ^ ((l15 & 7) << 4));
    const unsigned aB0 = lds_addr(&As[0][0]) + (unsigned)((wr * 128 + l15) * 128) + swz;
    const unsigned bB0 = lds_addr(&Bs[0][0]) + (unsigned)((wc * 64 + l15) * 128) + swz;

#define DSR(dst, addr, off) \
    asm volatile("ds_read_b128 %0, %1 offset:" #off : "=v"(dst) : "v"(addr))

    STG(0, 0);
    for (int kt = 0; kt < nK; ++kt) {
        const int bc = kt & 1;
        asm volatile("s_waitcnt vmcnt(0)\ns_barrier" ::: "memory");
        __builtin_amdgcn_sched_barrier(0);

        const unsigned aA0 = aB0 + bc * 32768;
        const unsigned aA1 = aA0 ^ 64u;
        const unsigned bA0 = bB0 + bc * 32768;
        const unsigned bA1 = bA0 ^ 64u;
        bf16x8 a00, a01, a02, a03, a04, a05, a06, a07;
        bf16x8 a10, a11, a12, a13, a14, a15, a16, a17;
        bf16x8 b00, b01, b02, b03, b10, b11, b12, b13;

        DSR(b00, bA0, 0);    DSR(b01, bA0, 2048);
        DSR(b02, bA0, 4096); DSR(b03, bA0, 6144);
        DSR(a00, aA0, 0);    DSR(a01, aA0, 2048);
        DSR(a02, aA0, 4096); DSR(a03, aA0, 6144);
        DSR(a04, aA0, 8192);  DSR(a05, aA0, 10240);
        DSR(a06, aA0, 12288); DSR(a07, aA0, 14336);

        if (kt + 1 < nK) STG(kt + 1, bc ^ 1);

        asm volatile("s_waitcnt lgkmcnt(4)" ::: "memory");
        __builtin_amdgcn_sched_barrier(0);
        __builtin_amdgcn_s_setprio(1);
        acc[0][0] = MFMA16(a00, b00, acc[0][0]); acc[0][1] = MFMA16(a00, b01, acc[0][1]);
        acc[0][2] = MFMA16(a00, b02, acc[0][2]); acc[0][3] = MFMA16(a00, b03, acc[0][3]);
        acc[1][0] = MFMA16(a01, b00, acc[1][0]); acc[1][1] = MFMA16(a01, b01, acc[1][1]);
        acc[1][2] = MFMA16(a01, b02, acc[1][2]); acc[1][3] = MFMA16(a01, b03, acc[1][3]);
        acc[2][0] = MFMA16(a02, b00, acc[2][0]); acc[2][1] = MFMA16(a02, b01, acc[2][1]);
        acc[2][2] = MFMA16(a02, b02, acc[2][2]); acc[2][3] = MFMA16(a02, b03, acc[2][3]);
        acc[3][0] = MFMA16(a03, b00, acc[3][0]); acc[3][1] = MFMA16(a03, b01, acc[3][1]);
        acc[3][2] = MFMA16(a03, b02, acc[3][2]); acc[3][3] = MFMA16(a03, b03, acc[3][3]);
        __builtin_amdgcn_s_setprio(0);

        DSR(b10, bA1, 0);    DSR(b11, bA1, 2048);
        DSR(b12, bA1, 4096); DSR(b13, bA1, 6144);
        DSR(a10, aA1, 0);    DSR(a11, aA1, 2048);
        DSR(a12, aA1, 4096); DSR(a13, aA1, 6144);

        asm volatile("s_waitcnt lgkmcnt(8)" ::: "memory");
        __builtin_amdgcn_sched_barrier(0);
        __builtin_amdgcn_s_setprio(1);
        acc[4][0] = MFMA16(a04, b00, acc[4][0]); acc[4][1] = MFMA16(a04, b01, acc[4][1]);
        acc[4][2] = MFMA16(a04, b02, acc[4][2]); acc[4][3] = MFMA16(a04, b03, acc[4][3]);
        acc[5][0] = MFMA16(a05, b00, acc[5][0]); acc[5][1] = MFMA16(a05, b01, acc[5][1]);
        acc[5][2] = MFMA16(a05, b02, acc[5][2]); acc[5][3] = MFMA16(a05, b03, acc[5][3]);
        acc[6][0] = MFMA16(a06, b00, acc[6][0]); acc[6][1] = MFMA16(a06, b01, acc[6][1]);
        acc[6][2] = MFMA16(a06, b02, acc[6][2]); acc[6][3] = MFMA16(a06, b03, acc[6][3]);
        acc[7][0] = MFMA16(a07, b00, acc[7][0]); acc[7][1] = MFMA16(a07, b01, acc[7][1]);
        acc[7][2] = MFMA16(a07, b02, acc[7][2]); acc[7][3] = MFMA16(a07, b03, acc[7][3]);
        __builtin_amdgcn_s_setprio(0);

        DSR(a14, aA1, 8192);  DSR(a15, aA1, 10240);
        DSR(a16, aA1, 12288); DSR(a17, aA1, 14336);

        asm volatile("s_waitcnt lgkmcnt(4)" ::: "memory");
        __builtin_amdgcn_sched_barrier(0);
        __builtin_amdgcn_s_setprio(1);
        acc[0][0] = MFMA16(a10, b10, acc[0][0]); acc[0][1] = MFMA16(a10, b11, acc[0][1]);
        acc[0][2] = MFMA16(a10, b12, acc[0][2]); acc[0][3] = MFMA16(a10, b13, acc[0][3]);
        acc[1][0] = MFMA16(a11, b10, acc[1][0]); acc[1][1] = MFMA16(a11, b11, acc[1][1]);
        acc[1][2] = MFMA16(a11, b12, acc[1][2]); acc[1][3] = MFMA16(a11, b13, acc[1][3]);
        acc[2][0] = MFMA16(a12, b10, acc[2][0]); acc[2][1] = MFMA16(a12, b11, acc[2][1]);
        acc[2][2] = MFMA16(a12, b12, acc[2][2]); acc[2][3] = MFMA16(a12, b13, acc[2][3]);
        acc[3][0] = MFMA16(a13, b10, acc[3][0]); acc[3][1] = MFMA16(a13, b11, acc[3][1]);
        acc[3][2] = MFMA16(a13, b12, acc[3][2]); acc[3][3] = MFMA16(a13, b13, acc[3][3]);
        __builtin_amdgcn_s_setprio(0);

        asm volatile("s_waitcnt lgkmcnt(0)" ::: "memory");
        __builtin_amdgcn_sched_barrier(0);
        __builtin_amdgcn_s_setprio(1);
        acc[4][0] = MFMA16(a14, b10, acc[4][0]); acc[4][1] = MFMA16(a14, b11, acc[4][1]);
        acc[4][2] = MFMA16(a14, b12, acc[4][2]); acc[4][3] = MFMA16(a14, b13, acc[4][3]);
        acc[5][0] = MFMA16(a15, b10, acc[5][0]); acc[5][1] = MFMA16(a15, b11, acc[5][1]);
        acc[5][2] = MFMA16(a15, b12, acc[5][2]); acc[5][3] = MFMA16(a15, b13, acc[5][3]);
        acc[6][0] = MFMA16(a16, b10, acc[6][0]); acc[6][1] = MFMA16(a16, b11, acc[6][1]);
        acc[6][2] = MFMA16(a16, b12, acc[6][2]); acc[6][3] = MFMA16(a16, b13, acc[6][3]);
        acc[7][0] = MFMA16(a17, b10, acc[7][0]); acc[7][1] = MFMA16(a17, b11, acc[7][1]);
        acc[7][2] = MFMA16(a17, b12, acc[7][2]); acc[7][3] = MFMA16(a17, b13, acc[7][3]);
        __builtin_amdgcn_s_setprio(0);
    }
#undef STG
#undef DSR

    for (int m = 0; m < 8; ++m)
        for (int n = 0; n < 4; ++n)
            for (int j = 0; j < 4; ++j) {
                int row = bm * 256 + wr * 128 + m * 16 + l4 * 4 + j;
                int col = bn * 256 + wc * 64 + n * 16 + l15;
                C[(size_t)row * N + col] = f2bf_fast(acc[m][n][j]);
            }
}

// ---------------------------------------------------------------- V transpose: Vb [4][2048][128] -> VbT (k-permuted per 64)
__global__ __launch_bounds__(256) void transpose_v(const unsigned short* __restrict__ Vb,
                                                   unsigned short* __restrict__ VbT) {
    const int kt = blockIdx.x;  // 0..31
    const int h  = blockIdx.y;  // 0..3
    __shared__ unsigned short T[64 * 132];
    const int tid = threadIdx.x;
    for (int i = 0; i < 4; ++i) {
        int s = i * 256 + tid;
        int r = s >> 4, c = (s & 15) * 8;
        us8 v = *(const us8*)(Vb + ((size_t)h * 2048 + kt * 64 + r) * 128 + c);
        *(us8*)&T[r * 132 + c] = v;
    }
    __syncthreads();
    for (int i = 0; i < 4; ++i) {
        int s = i * 256 + tid;
        int d = s >> 3, ck = (s & 7) * 8;
        us8 v;
        for (int j = 0; j < 8; ++j) {
            int c = ck + j;
            int k = (c & 3) * 16 + (c >> 2);
            v[j] = T[k * 132 + d];
        }
        *(us8*)(VbT + (size_t)h * 128 * 2048 + (size_t)d * 2048 + kt * 64 + ck) = v;
    }
}

// ---------------------------------------------------------------- flash attention: R9 form (proven 40us)
__global__ __launch_bounds__(512) void attn_fwd(const unsigned short* __restrict__ Qb,
                                                const unsigned short* __restrict__ Kb,
                                                const unsigned short* __restrict__ VbT,
                                                unsigned short* __restrict__ Ob) {
    const int bid = blockIdx.x;
    const int p = bid & 7;
    const int qt = bid >> 3;
    const int q0 = qt * 64;
    __shared__ unsigned short Ks[2][64 * 128];
    __shared__ unsigned short Vs[128 * 64];
    __shared__ char PsB[8][16 * 136];
    const int tid = threadIdx.x;
    const int lane = tid & 63, wave = tid >> 6;
    const int l15 = lane & 15, l4 = lane >> 4;
    const int h = 2 * p + (wave >> 2);
    const int rgrp = wave & 3;
    const int kvh = p >> 1;

    bf16x8 qf[4];
    {
        const unsigned short* qrow =
            Qb + ((size_t)h * 2048 + q0 + rgrp * 16 + l15) * 128 + l4 * 8;
        for (int kk = 0; kk < 4; ++kk) qf[kk] = *(const bf16x8*)(qrow + kk * 32);
    }
    f32x4 o[8] = {};
    float m2[4], lp[4];
    for (int j = 0; j < 4; ++j) { m2[j] = -1e30f; lp[j] = 0.0f; }
    const int kt_lo = (qt >= 16) ? (qt - 16) : 0;

    const unsigned short* Kh = Kb + (size_t)kvh * 2048 * 128;
    const unsigned short* Vh = VbT + (size_t)kvh * 128 * 2048;

    int ksr[2], ksc[2], vsr[2], vsc[2];
    for (int i = 0; i < 2; ++i) {
        int s = i * 512 + tid;
        ksr[i] = s >> 4;
        ksc[i] = (((s & 15) * 16) ^ ((ksr[i] & 7) << 4)) >> 1;
        vsr[i] = s >> 3;
        vsc[i] = (((s & 7) * 16) ^ ((vsr[i] & 7) << 4)) >> 1;
    }

    for (int i = 0; i < 2; ++i)
        gload_lds16(Kh + (size_t)(kt_lo * 64 + ksr[i]) * 128 + ksc[i],
                    &Ks[0][(i * 512 + tid) * 8]);

    int cur = 0;
    for (int kt = kt_lo; kt <= qt; ++kt) {
        asm volatile("s_waitcnt vmcnt(0)\ns_barrier" ::: "memory");
        __builtin_amdgcn_sched_barrier(0);

        for (int i = 0; i < 2; ++i)
            gload_lds16(Vh + (size_t)vsr[i] * 2048 + kt * 64 + vsc[i],
                        &Vs[(i * 512 + tid) * 8]);
        if (kt < qt) {
            for (int i = 0; i < 2; ++i)
                gload_lds16(Kh + (size_t)((kt + 1) * 64 + ksr[i]) * 128 + ksc[i],
                            &Ks[cur ^ 1][(i * 512 + tid) * 8]);
        }

        f32x4 s[4] = {};
        __builtin_amdgcn_s_setprio(1);
        for (int nn = 0; nn < 4; ++nn)
            for (int kk = 0; kk < 4; ++kk) {
                int r = nn * 16 + l15;
                int cb = (kk * 64 + l4 * 16) ^ ((r & 7) << 4);
                bf16x8 kf = *(const bf16x8*)((const char*)&Ks[cur][0] + r * 256 + cb);
                s[nn] = MFMA16(qf[kk], kf, s[nn]);
            }
        __builtin_amdgcn_s_setprio(0);

        float pv4[4][4];
        const bool masked = (kt == qt) || (qt >= 16 && kt == kt_lo);
        if (masked) {
            for (int nn = 0; nn < 4; ++nn) {
                int kc = kt * 64 + nn * 16 + l15;
                for (int j = 0; j < 4; ++j) {
                    int qr = q0 + rgrp * 16 + l4 * 4 + j;
                    unsigned diff = (unsigned)(qr - kc);
                    pv4[nn][j] = (diff < 1024u) ? s[nn][j] : -1e30f;
                }
            }
        } else {
            for (int nn = 0; nn < 4; ++nn)
                for (int j = 0; j < 4; ++j) pv4[nn][j] = s[nn][j];
        }

        float mxl[4];
        bool flag = true;
        for (int j = 0; j < 4; ++j) {
            mxl[j] = fmaxf(fmaxf(pv4[0][j], pv4[1][j]), fmaxf(pv4[2][j], pv4[3][j]));
            flag = flag && (mxl[j] <= m2[j] + 11.0f);
        }
        if (!__all(flag)) {
            for (int j = 0; j < 4; ++j) {
                float mx = mxl[j];
                for (int mk = 8; mk; mk >>= 1) mx = fmaxf(mx, __shfl_xor(mx, mk));
                float mnew = fmaxf(m2[j], mx);
                float corr = exp2f(m2[j] - mnew);
                m2[j] = mnew;
                lp[j] *= corr;
                for (int dd = 0; dd < 8; ++dd) o[dd][j] *= corr;
            }
        }
        for (int j = 0; j < 4; ++j) {
            float rs = 0.0f;
            for (int nn = 0; nn < 4; ++nn) {
                float pv = exp2f(pv4[nn][j] - m2[j]);
                pv4[nn][j] = pv;
                rs += pv;
            }
            lp[j] += rs;
        }

        for (int j = 0; j < 4; ++j) {
            int row = l4 * 4 + j;
            unsigned lo, hi;
            asm("v_cvt_pk_bf16_f32 %0, %1, %2" : "=v"(lo) : "v"(pv4[0][j]), "v"(pv4[1][j]));
            asm("v_cvt_pk_bf16_f32 %0, %1, %2" : "=v"(hi) : "v"(pv4[2][j]), "v"(pv4[3][j]));
            int cb = (l15 * 8) ^ ((row & 7) << 4);
            *(uint2*)(&PsB[wave][0] + row * 136 + cb) = make_uint2(lo, hi);
        }

        bf16x8 pa[2];
        for (int kk2 = 0; kk2 < 2; ++kk2) {
            int cb = (kk2 * 64 + l4 * 16) ^ ((l15 & 7) << 4);
            pa[kk2] = *(const bf16x8*)(&PsB[wave][0] + l15 * 136 + cb);
        }

        if (kt < qt)
            asm volatile("s_waitcnt vmcnt(2)\ns_barrier" ::: "memory");
        else
            asm volatile("s_waitcnt vmcnt(0)\ns_barrier" ::: "memory");
        __builtin_amdgcn_sched_barrier(0);

        __builtin_amdgcn_s_setprio(1);
        for (int dd = 0; dd < 8; ++dd)
            for (int kk2 = 0; kk2 < 2; ++kk2) {
                int d = dd * 16 + l15;
                int cb = (kk2 * 64 + l4 * 16) ^ ((d & 7) << 4);
                bf16x8 vf = *(const bf16x8*)((const char*)&Vs[0] + d * 128 + cb);
                o[dd] = MFMA16(pa[kk2], vf, o[dd]);
            }
        __builtin_amdgcn_s_setprio(0);
        cur ^= 1;
    }

    for (int j = 0; j < 4; ++j) {
        float lt = lp[j];
        for (int mk = 8; mk; mk >>= 1) lt += __shfl_xor(lt, mk);
        float inv = 1.0f / lt;
        int row = q0 + rgrp * 16 + l4 * 4 + j;
        unsigned short* orow = Ob + (size_t)row * 2048 + h * 128;
        for (int dd = 0; dd < 8; ++dd) orow[dd * 16 + l15] = f2bf_fast(o[dd][j] * inv);
    }
}

// ---------------------------------------------------------------- combine 4 bf16 split-K partials -> f32 out
__global__ __launch_bounds__(256) void add4(const unsigned short* __restrict__ p,
                                            float* __restrict__ out, int n) {
    int i = (blockIdx.x * 256 + threadIdx.x) * 8;
    if (i >= n) return;
    us8 a = *(const us8*)(p + i);
    us8 b = *(const us8*)(p + 4194304 + i);
    us8 c = *(const us8*)(p + 8388608 + i);
    us8 d = *(const us8*)(p + 12582912 + i);
    f32x4 o0, o1;
    for (int j = 0; j < 4; ++j)
        o0[j] = (bf2f(a[j]) + bf2f(b[j])) + (bf2f(c[j]) + bf2f(d[j]));
    for (int j = 0; j < 4; ++j)
        o1[j] = (bf2f(a[j + 4]) + bf2f(b[j + 4])) + (bf2f(c[j + 4]) + bf2f(d[j + 4]));
    *(f32x4*)(out + i) = o0;
    *(f32x4*)(out + i + 4) = o1;
}

// ---------------------------------------------------------------- launch
extern "C" void kernel_launch(void* const* d_in, const int* in_sizes, int n_in,
                              void* d_out, int out_size, void* d_ws, size_t ws_size,
                              hipStream_t stream) {
    const float* x  = (const float*)d_in[0];
    const float* wq = (const float*)d_in[1];
    const float* wk = (const float*)d_in[2];
    const float* wv = (const float*)d_in[3];
    const float* wo = (const float*)d_in[4];
    const float* qw = (const float*)d_in[5];
    const float* kw = (const float*)d_in[6];
    float* out = (float*)d_out;

    char* ws = (char*)d_ws;
    unsigned short* xb   = (unsigned short*)(ws + 0);          //  8 MB
    unsigned short* wqkv = (unsigned short*)(ws + 8388608);    // 12 MB
    unsigned short* wob  = (unsigned short*)(ws + 20971520);   //  8 MB
    unsigned short* Vb   = (unsigned short*)(ws + 29360128);   //  2 MB
    unsigned short* Qb   = (unsigned short*)(ws + 54525952);   //  8 MB
    unsigned short* Kb   = (unsigned short*)(ws + 62914560);   //  2 MB
    unsigned short* VbT  = (unsigned short*)(ws + 65011712);   //  2 MB
    unsigned short* Ob   = (unsigned short*)(ws + 67108864);   //  8 MB
    unsigned short* outP = (unsigned short*)(ws + 31457280);   // 32 MB bf16 x4 (after Vb; Qb region free post-attn? no - used during gemm; keep separate)
    float2*         tbl  = (float2*)(ws + 104857600);          //  1 MB

    prep_all<<<dim3(14848), dim3(256), 0, stream>>>(x, wq, wk, wv, wo, xb, wqkv, wob, tbl);
    gemm_qkv128<<<dim3(12, 16), dim3(512), 0, stream>>>(xb, wqkv, qw, kw, tbl, Qb, Kb, Vb);
    transpose_v<<<dim3(32, 4), dim3(256), 0, stream>>>(Vb, VbT);
    attn_fwd<<<dim3(256), dim3(512), 0, stream>>>(Qb, Kb, VbT, Ob);
    gemm256<<<dim3(8, 8, 4), dim3(512), 0, stream>>>(Ob, wob, outP, 2048, 2048, 2048, 512);
    add4<<<dim3(2048), dim3(256), 0, stream>>>(outP, out, 2048 * 2048);
}

// Round 20
// 123.125 us; speedup vs baseline: 1.0303x; 1.0303x over previous
//
#include <hip/hip_runtime.h>
#include <hip/hip_bf16.h>
#include <cstdint>
#include <cstddef>

typedef __attribute__((ext_vector_type(4))) float f32x4;
typedef __attribute__((ext_vector_type(8))) short bf16x8;
typedef __attribute__((ext_vector_type(8))) unsigned short us8;

#define MFMA16(a, b, c) __builtin_amdgcn_mfma_f32_16x16x32_bf16(a, b, c, 0, 0, 0)

__device__ inline unsigned short f2bf(float f) {
    unsigned int u = __float_as_uint(f);
    u += 0x7fffu + ((u >> 16) & 1u);
    return (unsigned short)(u >> 16);
}
__device__ inline float bf2f(unsigned short u) {
    return __uint_as_float((unsigned int)u << 16);
}
// 1-instruction bf16 convert (RTNE) via packed cvt
__device__ inline unsigned short f2bf_fast(float f) {
    float r;
    asm("v_cvt_pk_bf16_f32 %0, %1, %2" : "=v"(r) : "v"(f), "v"(f));
    return (unsigned short)__float_as_uint(r);
}

__device__ inline void gload_lds16(const void* g, void* l) {
    __builtin_amdgcn_global_load_lds(
        (const __attribute__((address_space(1))) void*)g,
        (__attribute__((address_space(3))) void*)l, 16, 0, 0);
}
__device__ inline unsigned lds_addr(const void* p) {
    return (unsigned)(size_t)((__attribute__((address_space(3))) const void*)p);
}

// ---------------------------------------------------------------- fused prep: 5 f32->bf16 converts + RoPE table
__global__ __launch_bounds__(256) void prep_all(const float* __restrict__ x,
                                                const float* __restrict__ wq,
                                                const float* __restrict__ wk,
                                                const float* __restrict__ wv,
                                                const float* __restrict__ wo,
                                                unsigned short* __restrict__ xb,
                                                unsigned short* __restrict__ wqkv,
                                                unsigned short* __restrict__ wob,
                                                float2* __restrict__ tbl) {
    const int b = blockIdx.x;
    if (b < 14336) {
        const float* src; unsigned short* dst; int off4;
        if (b < 4096)       { src = x;  dst = xb;                 off4 = b; }
        else if (b < 8192)  { src = wq; dst = wqkv;               off4 = b - 4096; }
        else if (b < 9216)  { src = wk; dst = wqkv + 2048 * 2048; off4 = b - 8192; }
        else if (b < 10240) { src = wv; dst = wqkv + 2560 * 2048; off4 = b - 9216; }
        else                { src = wo; dst = wob;                off4 = b - 10240; }
        int i = (off4 * 256 + threadIdx.x) * 4;
        float4 v = *(const float4*)(src + i);
        ushort4 o;
        o.x = f2bf(v.x); o.y = f2bf(v.y); o.z = f2bf(v.z); o.w = f2bf(v.w);
        *(ushort4*)(dst + i) = o;
    } else {
        int idx = (b - 14336) * 256 + threadIdx.x;
        int row = idx >> 6, t = idx & 63;
        float inv_freq = exp2f((float)t * (-2.0f / 128.0f) * 13.287712379549449f);
        float s, c;
        sincosf((float)row * inv_freq, &s, &c);
        tbl[idx] = make_float2(c, s);
    }
}

// ---------------------------------------------------------------- gemm256: BK=64, 2-buffer, 4 counted-lgkm MFMA sub-phases
__global__ __launch_bounds__(512, 1) void gemm256(const unsigned short* __restrict__ A,
                                                  const unsigned short* __restrict__ B,
                                                  unsigned short* __restrict__ Cp,
                                                  int M, int N, int Kfull, int kspan) {
    __shared__ unsigned short As[2][16384];   // 32KB each buf
    __shared__ unsigned short Bs[2][16384];
    const int tid = threadIdx.x;
    const int lane = tid & 63, wave = tid >> 6;
    const int wr = wave >> 2, wc = wave & 3;
    const int l15 = lane & 15, l4 = lane >> 4;
    const int gx = gridDim.x;
    const int nwg = gx * gridDim.y;
    const int bid0 = blockIdx.y * gx + blockIdx.x;
    const int q8 = nwg >> 3, r8 = nwg & 7;
    const int xcd = bid0 & 7, sub = bid0 >> 3;
    const int wgid = ((xcd < r8) ? xcd * (q8 + 1) : r8 * (q8 + 1) + (xcd - r8) * q8) + sub;
    const int bm = wgid / gx, bn = wgid % gx;
    const int z = blockIdx.z;
    const unsigned short* Az = A + (size_t)z * kspan;
    const unsigned short* Bz = B + (size_t)z * kspan;
    unsigned short* C = Cp + (size_t)z * M * N;
    const int nK = kspan >> 6;   // BK=64

    f32x4 acc[8][4] = {};

    const int sA0 = tid, sA1 = 512 + tid, sA2 = 1024 + tid, sA3 = 1536 + tid;
#define SRCOF(s) ((((((s) & 7) * 16) ^ ((((s) >> 3) & 7) << 4)) >> 1))
    const unsigned short* pa0 = Az + (size_t)(bm * 256 + (sA0 >> 3)) * Kfull + SRCOF(sA0);
    const unsigned short* pa1 = Az + (size_t)(bm * 256 + (sA1 >> 3)) * Kfull + SRCOF(sA1);
    const unsigned short* pa2 = Az + (size_t)(bm * 256 + (sA2 >> 3)) * Kfull + SRCOF(sA2);
    const unsigned short* pa3 = Az + (size_t)(bm * 256 + (sA3 >> 3)) * Kfull + SRCOF(sA3);
    const unsigned short* pb0 = Bz + (size_t)(bn * 256 + (sA0 >> 3)) * Kfull + SRCOF(sA0);
    const unsigned short* pb1 = Bz + (size_t)(bn * 256 + (sA1 >> 3)) * Kfull + SRCOF(sA1);
    const unsigned short* pb2 = Bz + (size_t)(bn * 256 + (sA2 >> 3)) * Kfull + SRCOF(sA2);
    const unsigned short* pb3 = Bz + (size_t)(bn * 256 + (sA3 >> 3)) * Kfull + SRCOF(sA3);
#undef SRCOF

#define STG(kt, bb)                                           \
    do {                                                      \
        gload_lds16(pa0 + (kt) * 64, &As[bb][sA0 * 8]);       \
        gload_lds16(pa1 + (kt) * 64, &As[bb][sA1 * 8]);       \
        gload_lds16(pa2 + (kt) * 64, &As[bb][sA2 * 8]);       \
        gload_lds16(pa3 + (kt) * 64, &As[bb][sA3 * 8]);       \
        gload_lds16(pb0 + (kt) * 64, &Bs[bb][sA0 * 8]);       \
        gload_lds16(pb1 + (kt) * 64, &Bs[bb][sA1 * 8]);       \
        gload_lds16(pb2 + (kt) * 64, &Bs[bb][sA2 * 8]);       \
        gload_lds16(pb3 + (kt) * 64, &Bs[bb][sA3 * 8]);       \
    } while (0)

    const unsigned swz = (unsigned)((l4 * 16) ^ ((l15 & 7) << 4));
    const unsigned aB0 = lds_addr(&As[0][0]) + (unsigned)((wr * 128 + l15) * 128) + swz;
    const unsigned bB0 = lds_addr(&Bs[0][0]) + (unsigned)((wc * 64 + l15) * 128) + swz;

#define DSR(dst, addr, off) \
    asm volatile("ds_read_b128 %0, %1 offset:" #off : "=v"(dst) : "v"(addr))

    STG(0, 0);
    for (int kt = 0; kt < nK; ++kt) {
        const int bc = kt & 1;
        asm volatile("s_waitcnt vmcnt(0)\ns_barrier" ::: "memory");
        __builtin_amdgcn_sched_barrier(0);

        const unsigned aA0 = aB0 + bc * 32768;
        const unsigned aA1 = aA0 ^ 64u;
        const unsigned bA0 = bB0 + bc * 32768;
        const unsigned bA1 = bA0 ^ 64u;
        bf16x8 a00, a01, a02, a03, a04, a05, a06, a07;
        bf16x8 a10, a11, a12, a13, a14, a15, a16, a17;
        bf16x8 b00, b01, b02, b03, b10, b11, b12, b13;

        // group1: B-ks0 (4) + A-ks0 m0-3 (4)
        DSR(b00, bA0, 0);    DSR(b01, bA0, 2048);
        DSR(b02, bA0, 4096); DSR(b03, bA0, 6144);
        DSR(a00, aA0, 0);    DSR(a01, aA0, 2048);
        DSR(a02, aA0, 4096); DSR(a03, aA0, 6144);
        // group2: A-ks0 m4-7 (4)
        DSR(a04, aA0, 8192);  DSR(a05, aA0, 10240);
        DSR(a06, aA0, 12288); DSR(a07, aA0, 14336);

        if (kt + 1 < nK) STG(kt + 1, bc ^ 1);

        asm volatile("s_waitcnt lgkmcnt(4)" ::: "memory");   // group1 done
        __builtin_amdgcn_sched_barrier(0);
        __builtin_amdgcn_s_setprio(1);
        acc[0][0] = MFMA16(a00, b00, acc[0][0]); acc[0][1] = MFMA16(a00, b01, acc[0][1]);
        acc[0][2] = MFMA16(a00, b02, acc[0][2]); acc[0][3] = MFMA16(a00, b03, acc[0][3]);
        acc[1][0] = MFMA16(a01, b00, acc[1][0]); acc[1][1] = MFMA16(a01, b01, acc[1][1]);
        acc[1][2] = MFMA16(a01, b02, acc[1][2]); acc[1][3] = MFMA16(a01, b03, acc[1][3]);
        acc[2][0] = MFMA16(a02, b00, acc[2][0]); acc[2][1] = MFMA16(a02, b01, acc[2][1]);
        acc[2][2] = MFMA16(a02, b02, acc[2][2]); acc[2][3] = MFMA16(a02, b03, acc[2][3]);
        acc[3][0] = MFMA16(a03, b00, acc[3][0]); acc[3][1] = MFMA16(a03, b01, acc[3][1]);
        acc[3][2] = MFMA16(a03, b02, acc[3][2]); acc[3][3] = MFMA16(a03, b03, acc[3][3]);
        __builtin_amdgcn_s_setprio(0);

        // group3: B-ks1 (4) + A-ks1 m0-3 (4)
        DSR(b10, bA1, 0);    DSR(b11, bA1, 2048);
        DSR(b12, bA1, 4096); DSR(b13, bA1, 6144);
        DSR(a10, aA1, 0);    DSR(a11, aA1, 2048);
        DSR(a12, aA1, 4096); DSR(a13, aA1, 6144);

        asm volatile("s_waitcnt lgkmcnt(8)" ::: "memory");   // group2 done
        __builtin_amdgcn_sched_barrier(0);
        __builtin_amdgcn_s_setprio(1);
        acc[4][0] = MFMA16(a04, b00, acc[4][0]); acc[4][1] = MFMA16(a04, b01, acc[4][1]);
        acc[4][2] = MFMA16(a04, b02, acc[4][2]); acc[4][3] = MFMA16(a04, b03, acc[4][3]);
        acc[5][0] = MFMA16(a05, b00, acc[5][0]); acc[5][1] = MFMA16(a05, b01, acc[5][1]);
        acc[5][2] = MFMA16(a05, b02, acc[5][2]); acc[5][3] = MFMA16(a05, b03, acc[5][3]);
        acc[6][0] = MFMA16(a06, b00, acc[6][0]); acc[6][1] = MFMA16(a06, b01, acc[6][1]);
        acc[6][2] = MFMA16(a06, b02, acc[6][2]); acc[6][3] = MFMA16(a06, b03, acc[6][3]);
        acc[7][0] = MFMA16(a07, b00, acc[7][0]); acc[7][1] = MFMA16(a07, b01, acc[7][1]);
        acc[7][2] = MFMA16(a07, b02, acc[7][2]); acc[7][3] = MFMA16(a07, b03, acc[7][3]);
        __builtin_amdgcn_s_setprio(0);

        // group4: A-ks1 m4-7 (4)
        DSR(a14, aA1, 8192);  DSR(a15, aA1, 10240);
        DSR(a16, aA1, 12288); DSR(a17, aA1, 14336);

        asm volatile("s_waitcnt lgkmcnt(4)" ::: "memory");   // group3 done
        __builtin_amdgcn_sched_barrier(0);
        __builtin_amdgcn_s_setprio(1);
        acc[0][0] = MFMA16(a10, b10, acc[0][0]); acc[0][1] = MFMA16(a10, b11, acc[0][1]);
        acc[0][2] = MFMA16(a10, b12, acc[0][2]); acc[0][3] = MFMA16(a10, b13, acc[0][3]);
        acc[1][0] = MFMA16(a11, b10, acc[1][0]); acc[1][1] = MFMA16(a11, b11, acc[1][1]);
        acc[1][2] = MFMA16(a11, b12, acc[1][2]); acc[1][3] = MFMA16(a11, b13, acc[1][3]);
        acc[2][0] = MFMA16(a12, b10, acc[2][0]); acc[2][1] = MFMA16(a12, b11, acc[2][1]);
        acc[2][2] = MFMA16(a12, b12, acc[2][2]); acc[2][3] = MFMA16(a12, b13, acc[2][3]);
        acc[3][0] = MFMA16(a13, b10, acc[3][0]); acc[3][1] = MFMA16(a13, b11, acc[3][1]);
        acc[3][2] = MFMA16(a13, b12, acc[3][2]); acc[3][3] = MFMA16(a13, b13, acc[3][3]);
        __builtin_amdgcn_s_setprio(0);

        asm volatile("s_waitcnt lgkmcnt(0)" ::: "memory");   // group4 done
        __builtin_amdgcn_sched_barrier(0);
        __builtin_amdgcn_s_setprio(1);
        acc[4][0] = MFMA16(a14, b10, acc[4][0]); acc[4][1] = MFMA16(a14, b11, acc[4][1]);
        acc[4][2] = MFMA16(a14, b12, acc[4][2]); acc[4][3] = MFMA16(a14, b13, acc[4][3]);
        acc[5][0] = MFMA16(a15, b10, acc[5][0]); acc[5][1] = MFMA16(a15, b11, acc[5][1]);
        acc[5][2] = MFMA16(a15, b12, acc[5][2]); acc[5][3] = MFMA16(a15, b13, acc[5][3]);
        acc[6][0] = MFMA16(a16, b10, acc[6][0]); acc[6][1] = MFMA16(a16, b11, acc[6][1]);
        acc[6][2] = MFMA16(a16, b12, acc[6][2]); acc[6][3] = MFMA16(a16, b13, acc[6][3]);
        acc[7][0] = MFMA16(a17, b10, acc[7][0]); acc[7][1] = MFMA16(a17, b11, acc[7][1]);
        acc[7][2] = MFMA16(a17, b12, acc[7][2]); acc[7][3] = MFMA16(a17, b13, acc[7][3]);
        __builtin_amdgcn_s_setprio(0);
    }
#undef STG
#undef DSR

    for (int m = 0; m < 8; ++m)
        for (int n = 0; n < 4; ++n)
            for (int j = 0; j < 4; ++j) {
                int row = bm * 256 + wr * 128 + m * 16 + l4 * 4 + j;
                int col = bn * 256 + wc * 64 + n * 16 + l15;
                C[(size_t)row * N + col] = f2bf_fast(acc[m][n][j]);
            }
}

// ---------------------------------------------------------------- combine + RMSNorm + RoPE (Q/K heads; Q pre-scaled)
__global__ __launch_bounds__(256) void norm_rope(const unsigned short* __restrict__ p0,
                                                 const unsigned short* __restrict__ p1,
                                                 const float* __restrict__ qw,
                                                 const float* __restrict__ kw,
                                                 const float2* __restrict__ tbl,
                                                 unsigned short* __restrict__ Qb,
                                                 unsigned short* __restrict__ Kb) {
    const int row = blockIdx.x;
    const int head = blockIdx.y * 4 + (threadIdx.x >> 6);  // 0..19
    const int t = threadIdx.x & 63;
    const size_t off = (size_t)row * 3072 + head * 128;
    float x1 = bf2f(p0[off + t]) + bf2f(p1[off + t]);
    float x2 = bf2f(p0[off + t + 64]) + bf2f(p1[off + t + 64]);
    float ss = x1 * x1 + x2 * x2;
    for (int m = 32; m; m >>= 1) ss += __shfl_xor(ss, m);
    float r = rsqrtf(ss * (1.0f / 128.0f) + 1e-6f);
    const float* w = (head < 16) ? qw : kw;
    float y1 = x1 * r * w[t], y2 = x2 * r * w[t + 64];
    float2 cs = tbl[row * 64 + t];
    x1 = y1 * cs.x - y2 * cs.y;
    x2 = y1 * cs.y + y2 * cs.x;
    if (head < 16) {                       // fold softmax scale*log2(e) into Q
        const float SCALE2 = 0.12751879526654698f;
        x1 *= SCALE2; x2 *= SCALE2;
    }
    unsigned short* dst = (head < 16) ? Qb + ((size_t)head * 2048 + row) * 128
                                      : Kb + ((size_t)(head - 16) * 2048 + row) * 128;
    dst[t] = f2bf(x1);
    dst[t + 64] = f2bf(x2);
}

// ---------------------------------------------------------------- V: combine + transpose with k-permuted columns
// VbT[h][d][kt*64 + c'] = V[kt*64 + k(c')][d], k(c') = (c'&3)*16 + (c'>>2)
__global__ __launch_bounds__(256) void transpose_v(const unsigned short* __restrict__ p0,
                                                   const unsigned short* __restrict__ p1,
                                                   unsigned short* __restrict__ VbT) {
    const int kt = blockIdx.x;  // 0..31
    const int h  = blockIdx.y;  // 0..3
    __shared__ unsigned short T[64 * 132];
    const int tid = threadIdx.x;
    for (int i = 0; i < 8; ++i) {
        int s = i * 256 + tid;
        int r = s >> 5, c = (s & 31) * 4;
        size_t off = (size_t)(kt * 64 + r) * 3072 + (20 + h) * 128 + c;
        ushort4 a = *(const ushort4*)(p0 + off);
        ushort4 b = *(const ushort4*)(p1 + off);
        ushort4 o;
        o.x = f2bf(bf2f(a.x) + bf2f(b.x));
        o.y = f2bf(bf2f(a.y) + bf2f(b.y));
        o.z = f2bf(bf2f(a.z) + bf2f(b.z));
        o.w = f2bf(bf2f(a.w) + bf2f(b.w));
        *(ushort4*)&T[r * 132 + c] = o;
    }
    __syncthreads();
    for (int i = 0; i < 4; ++i) {
        int s = i * 256 + tid;
        int d = s >> 3, ck = (s & 7) * 8;
        us8 v;
        for (int j = 0; j < 8; ++j) {
            int c = ck + j;
            int k = (c & 3) * 16 + (c >> 2);
            v[j] = T[k * 132 + d];
        }
        *(us8*)(VbT + (size_t)h * 128 * 2048 + (size_t)d * 2048 + kt * 64 + ck) = v;
    }
}

// ---------------------------------------------------------------- flash attention: R9 form (proven 40us)
// 2 heads/block, KVBLK=64, 8 waves; K dbuf + single-V async stage
__global__ __launch_bounds__(512) void attn_fwd(const unsigned short* __restrict__ Qb,
                                                const unsigned short* __restrict__ Kb,
                                                const unsigned short* __restrict__ VbT,
                                                unsigned short* __restrict__ Ob) {
    const int bid = blockIdx.x;
    const int p = bid & 7;           // head pair = XCD slot
    const int qt = bid >> 3;         // 0..31
    const int q0 = qt * 64;
    __shared__ unsigned short Ks[2][64 * 128];   // swizzled
    __shared__ unsigned short Vs[128 * 64];      // V^T swizzled, k-permuted columns
    __shared__ char PsB[8][16 * 136];            // packed P, stride 136B
    const int tid = threadIdx.x;
    const int lane = tid & 63, wave = tid >> 6;
    const int l15 = lane & 15, l4 = lane >> 4;
    const int h = 2 * p + (wave >> 2);           // this wave's head
    const int rgrp = wave & 3;                   // 16-row group
    const int kvh = p >> 1;

    bf16x8 qf[4];
    {
        const unsigned short* qrow =
            Qb + ((size_t)h * 2048 + q0 + rgrp * 16 + l15) * 128 + l4 * 8;
        for (int kk = 0; kk < 4; ++kk) qf[kk] = *(const bf16x8*)(qrow + kk * 32);
    }
    f32x4 o[8] = {};
    float m2[4], lp[4];
    for (int j = 0; j < 4; ++j) { m2[j] = -1e30f; lp[j] = 0.0f; }
    const int kt_lo = (qt >= 16) ? (qt - 16) : 0;

    const unsigned short* Kh = Kb + (size_t)kvh * 2048 * 128;
    const unsigned short* Vh = VbT + (size_t)kvh * 128 * 2048;

    int ksr[2], ksc[2], vsr[2], vsc[2];
    for (int i = 0; i < 2; ++i) {
        int s = i * 512 + tid;
        ksr[i] = s >> 4;
        ksc[i] = (((s & 15) * 16) ^ ((ksr[i] & 7) << 4)) >> 1;
        vsr[i] = s >> 3;
        vsc[i] = (((s & 7) * 16) ^ ((vsr[i] & 7) << 4)) >> 1;
    }

    // prologue: K[kt_lo] -> Ks[0]
    for (int i = 0; i < 2; ++i)
        gload_lds16(Kh + (size_t)(kt_lo * 64 + ksr[i]) * 128 + ksc[i],
                    &Ks[0][(i * 512 + tid) * 8]);

    int cur = 0;
    for (int kt = kt_lo; kt <= qt; ++kt) {
        asm volatile("s_waitcnt vmcnt(0)\ns_barrier" ::: "memory");
        __builtin_amdgcn_sched_barrier(0);

        // issue V[kt] (oldest), then K[kt+1]
        for (int i = 0; i < 2; ++i)
            gload_lds16(Vh + (size_t)vsr[i] * 2048 + kt * 64 + vsc[i],
                        &Vs[(i * 512 + tid) * 8]);
        if (kt < qt) {
            for (int i = 0; i < 2; ++i)
                gload_lds16(Kh + (size_t)((kt + 1) * 64 + ksr[i]) * 128 + ksc[i],
                            &Ks[cur ^ 1][(i * 512 + tid) * 8]);
        }

        // S = Q K^T (Q pre-scaled -> log2 domain)
        f32x4 s[4] = {};
        __builtin_amdgcn_s_setprio(1);
        for (int nn = 0; nn < 4; ++nn)
            for (int kk = 0; kk < 4; ++kk) {
                int r = nn * 16 + l15;
                int cb = (kk * 64 + l4 * 16) ^ ((r & 7) << 4);
                bf16x8 kf = *(const bf16x8*)((const char*)&Ks[cur][0] + r * 256 + cb);
                s[nn] = MFMA16(qf[kk], kf, s[nn]);
            }
        __builtin_amdgcn_s_setprio(0);

        float pv4[4][4];
        const bool masked = (kt == qt) || (qt >= 16 && kt == kt_lo);
        if (masked) {
            for (int nn = 0; nn < 4; ++nn) {
                int kc = kt * 64 + nn * 16 + l15;
                for (int j = 0; j < 4; ++j) {
                    int qr = q0 + rgrp * 16 + l4 * 4 + j;
                    unsigned diff = (unsigned)(qr - kc);
                    pv4[nn][j] = (diff < 1024u) ? s[nn][j] : -1e30f;
                }
            }
        } else {
            for (int nn = 0; nn < 4; ++nn)
                for (int j = 0; j < 4; ++j) pv4[nn][j] = s[nn][j];
        }

        // deferred-max: common path has NO cross-lane reduce
        float mxl[4];
        bool flag = true;
        for (int j = 0; j < 4; ++j) {
            mxl[j] = fmaxf(fmaxf(pv4[0][j], pv4[1][j]), fmaxf(pv4[2][j], pv4[3][j]));
            flag = flag && (mxl[j] <= m2[j] + 11.0f);
        }
        if (!__all(flag)) {
            for (int j = 0; j < 4; ++j) {
                float mx = mxl[j];
                for (int mk = 8; mk; mk >>= 1) mx = fmaxf(mx, __shfl_xor(mx, mk));
                float mnew = fmaxf(m2[j], mx);
                float corr = exp2f(m2[j] - mnew);
                m2[j] = mnew;
                lp[j] *= corr;
                for (int dd = 0; dd < 8; ++dd) o[dd][j] *= corr;
            }
        }
        for (int j = 0; j < 4; ++j) {
            float rs = 0.0f;
            for (int nn = 0; nn < 4; ++nn) {
                float pv = exp2f(pv4[nn][j] - m2[j]);
                pv4[nn][j] = pv;
                rs += pv;
            }
            lp[j] += rs;
        }

        // packed P store: k-permuted cols (c' = l15*4 + nn), 1 b64 write per j
        for (int j = 0; j < 4; ++j) {
            int row = l4 * 4 + j;
            unsigned lo, hi;
            asm("v_cvt_pk_bf16_f32 %0, %1, %2" : "=v"(lo) : "v"(pv4[0][j]), "v"(pv4[1][j]));
            asm("v_cvt_pk_bf16_f32 %0, %1, %2" : "=v"(hi) : "v"(pv4[2][j]), "v"(pv4[3][j]));
            int cb = (l15 * 8) ^ ((row & 7) << 4);
            *(uint2*)(&PsB[wave][0] + row * 136 + cb) = make_uint2(lo, hi);
        }

        bf16x8 pa[2];
        for (int kk2 = 0; kk2 < 2; ++kk2) {
            int cb = (kk2 * 64 + l4 * 16) ^ ((l15 & 7) << 4);
            pa[kk2] = *(const bf16x8*)(&PsB[wave][0] + l15 * 136 + cb);
        }

        // V[kt] certified (this wave's 2 V-loads are its oldest); barrier collectivizes
        if (kt < qt)
            asm volatile("s_waitcnt vmcnt(2)\ns_barrier" ::: "memory");
        else
            asm volatile("s_waitcnt vmcnt(0)\ns_barrier" ::: "memory");
        __builtin_amdgcn_sched_barrier(0);

        __builtin_amdgcn_s_setprio(1);
        for (int dd = 0; dd < 8; ++dd)
            for (int kk2 = 0; kk2 < 2; ++kk2) {
                int d = dd * 16 + l15;
                int cb = (kk2 * 64 + l4 * 16) ^ ((d & 7) << 4);
                bf16x8 vf = *(const bf16x8*)((const char*)&Vs[0] + d * 128 + cb);
                o[dd] = MFMA16(pa[kk2], vf, o[dd]);
            }
        __builtin_amdgcn_s_setprio(0);
        cur ^= 1;
    }

    for (int j = 0; j < 4; ++j) {
        float lt = lp[j];
        for (int mk = 8; mk; mk >>= 1) lt += __shfl_xor(lt, mk);
        float inv = 1.0f / lt;
        int row = q0 + rgrp * 16 + l4 * 4 + j;
        unsigned short* orow = Ob + (size_t)row * 2048 + h * 128;
        for (int dd = 0; dd < 8; ++dd) orow[dd * 16 + l15] = f2bf_fast(o[dd][j] * inv);
    }
}

// ---------------------------------------------------------------- combine 4 bf16 split-K partials -> f32 out
__global__ __launch_bounds__(256) void add4(const unsigned short* __restrict__ p,
                                            float* __restrict__ out, int n) {
    int i = (blockIdx.x * 256 + threadIdx.x) * 8;
    if (i >= n) return;
    us8 a = *(const us8*)(p + i);
    us8 b = *(const us8*)(p + 4194304 + i);
    us8 c = *(const us8*)(p + 8388608 + i);
    us8 d = *(const us8*)(p + 12582912 + i);
    f32x4 o0, o1;
    for (int j = 0; j < 4; ++j)
        o0[j] = (bf2f(a[j]) + bf2f(b[j])) + (bf2f(c[j]) + bf2f(d[j]));
    for (int j = 0; j < 4; ++j)
        o1[j] = (bf2f(a[j + 4]) + bf2f(b[j + 4])) + (bf2f(c[j + 4]) + bf2f(d[j + 4]));
    *(f32x4*)(out + i) = o0;
    *(f32x4*)(out + i + 4) = o1;
}

// ---------------------------------------------------------------- launch
extern "C" void kernel_launch(void* const* d_in, const int* in_sizes, int n_in,
                              void* d_out, int out_size, void* d_ws, size_t ws_size,
                              hipStream_t stream) {
    const float* x  = (const float*)d_in[0];
    const float* wq = (const float*)d_in[1];
    const float* wk = (const float*)d_in[2];
    const float* wv = (const float*)d_in[3];
    const float* wo = (const float*)d_in[4];
    const float* qw = (const float*)d_in[5];
    const float* kw = (const float*)d_in[6];
    float* out = (float*)d_out;

    char* ws = (char*)d_ws;
    unsigned short* xb   = (unsigned short*)(ws + 0);          //  8 MB
    unsigned short* wqkv = (unsigned short*)(ws + 8388608);    // 12 MB
    unsigned short* wob  = (unsigned short*)(ws + 20971520);   //  8 MB
    unsigned short* qkvP = (unsigned short*)(ws + 29360128);   // 25 MB bf16 x2 partials
    unsigned short* Qb   = (unsigned short*)(ws + 54525952);   //  8 MB
    unsigned short* Kb   = (unsigned short*)(ws + 62914560);   //  2 MB
    unsigned short* VbT  = (unsigned short*)(ws + 65011712);   //  2 MB
    unsigned short* Ob   = (unsigned short*)(ws + 67108864);   //  8 MB
    unsigned short* outP = (unsigned short*)(ws + 29360128);   // 32 MB bf16 x4, overlays dead qkvP/Qb
    float2*         tbl  = (float2*)(ws + 104857600);          //  1 MB

    prep_all<<<dim3(14848), dim3(256), 0, stream>>>(x, wq, wk, wv, wo, xb, wqkv, wob, tbl);
    gemm256<<<dim3(12, 8, 2), dim3(512), 0, stream>>>(xb, wqkv, qkvP, 2048, 3072, 2048, 1024);
    norm_rope<<<dim3(2048, 5), dim3(256), 0, stream>>>(qkvP, qkvP + 2048 * 3072, qw, kw, tbl, Qb, Kb);
    transpose_v<<<dim3(32, 4), dim3(256), 0, stream>>>(qkvP, qkvP + 2048 * 3072, VbT);
    attn_fwd<<<dim3(256), dim3(512), 0, stream>>>(Qb, Kb, VbT, Ob);
    gemm256<<<dim3(8, 8, 4), dim3(512), 0, stream>>>(Ob, wob, outP, 2048, 2048, 2048, 512);
    add4<<<dim3(2048), dim3(256), 0, stream>>>(outP, out, 2048 * 2048);
}

// Round 21
// 121.369 us; speedup vs baseline: 1.0452x; 1.0145x over previous
//
#include <hip/hip_runtime.h>
#include <hip/hip_bf16.h>
#include <cstdint>
#include <cstddef>

typedef __attribute__((ext_vector_type(4))) float f32x4;
typedef __attribute__((ext_vector_type(8))) short bf16x8;
typedef __attribute__((ext_vector_type(8))) unsigned short us8;

#define MFMA16(a, b, c) __builtin_amdgcn_mfma_f32_16x16x32_bf16(a, b, c, 0, 0, 0)

__device__ inline unsigned short f2bf(float f) {
    unsigned int u = __float_as_uint(f);
    u += 0x7fffu + ((u >> 16) & 1u);
    return (unsigned short)(u >> 16);
}
__device__ inline float bf2f(unsigned short u) {
    return __uint_as_float((unsigned int)u << 16);
}
// 1-instruction bf16 convert (RTNE) via packed cvt
__device__ inline unsigned short f2bf_fast(float f) {
    float r;
    asm("v_cvt_pk_bf16_f32 %0, %1, %2" : "=v"(r) : "v"(f), "v"(f));
    return (unsigned short)__float_as_uint(r);
}

__device__ inline void gload_lds16(const void* g, void* l) {
    __builtin_amdgcn_global_load_lds(
        (const __attribute__((address_space(1))) void*)g,
        (__attribute__((address_space(3))) void*)l, 16, 0, 0);
}
__device__ inline unsigned lds_addr(const void* p) {
    return (unsigned)(size_t)((__attribute__((address_space(3))) const void*)p);
}

// ---------------------------------------------------------------- fused prep: 5 f32->bf16 converts + RoPE table
__global__ __launch_bounds__(256) void prep_all(const float* __restrict__ x,
                                                const float* __restrict__ wq,
                                                const float* __restrict__ wk,
                                                const float* __restrict__ wv,
                                                const float* __restrict__ wo,
                                                unsigned short* __restrict__ xb,
                                                unsigned short* __restrict__ wqkv,
                                                unsigned short* __restrict__ wob,
                                                float2* __restrict__ tbl) {
    const int b = blockIdx.x;
    if (b < 14336) {
        const float* src; unsigned short* dst; int off4;
        if (b < 4096)       { src = x;  dst = xb;                 off4 = b; }
        else if (b < 8192)  { src = wq; dst = wqkv;               off4 = b - 4096; }
        else if (b < 9216)  { src = wk; dst = wqkv + 2048 * 2048; off4 = b - 8192; }
        else if (b < 10240) { src = wv; dst = wqkv + 2560 * 2048; off4 = b - 9216; }
        else                { src = wo; dst = wob;                off4 = b - 10240; }
        int i = (off4 * 256 + threadIdx.x) * 4;
        float4 v = *(const float4*)(src + i);
        ushort4 o;
        o.x = f2bf(v.x); o.y = f2bf(v.y); o.z = f2bf(v.z); o.w = f2bf(v.w);
        *(ushort4*)(dst + i) = o;
    } else {
        int idx = (b - 14336) * 256 + threadIdx.x;
        int row = idx >> 6, t = idx & 63;
        float inv_freq = exp2f((float)t * (-2.0f / 128.0f) * 13.287712379549449f);
        float s, c;
        sincosf((float)row * inv_freq, &s, &c);
        tbl[idx] = make_float2(c, s);
    }
}

// ---------------------------------------------------------------- gemm256: BK=64, 2-buffer, 4 counted-lgkm MFMA sub-phases
__global__ __launch_bounds__(512, 1) void gemm256(const unsigned short* __restrict__ A,
                                                  const unsigned short* __restrict__ B,
                                                  unsigned short* __restrict__ Cp,
                                                  int M, int N, int Kfull, int kspan) {
    __shared__ unsigned short As[2][16384];   // 32KB each buf
    __shared__ unsigned short Bs[2][16384];
    const int tid = threadIdx.x;
    const int lane = tid & 63, wave = tid >> 6;
    const int wr = wave >> 2, wc = wave & 3;
    const int l15 = lane & 15, l4 = lane >> 4;
    const int gx = gridDim.x;
    const int nwg = gx * gridDim.y;
    const int bid0 = blockIdx.y * gx + blockIdx.x;
    const int q8 = nwg >> 3, r8 = nwg & 7;
    const int xcd = bid0 & 7, sub = bid0 >> 3;
    const int wgid = ((xcd < r8) ? xcd * (q8 + 1) : r8 * (q8 + 1) + (xcd - r8) * q8) + sub;
    const int bm = wgid / gx, bn = wgid % gx;
    const int z = blockIdx.z;
    const unsigned short* Az = A + (size_t)z * kspan;
    const unsigned short* Bz = B + (size_t)z * kspan;
    unsigned short* C = Cp + (size_t)z * M * N;
    const int nK = kspan >> 6;   // BK=64

    f32x4 acc[8][4] = {};

    const int sA0 = tid, sA1 = 512 + tid, sA2 = 1024 + tid, sA3 = 1536 + tid;
#define SRCOF(s) ((((((s) & 7) * 16) ^ ((((s) >> 3) & 7) << 4)) >> 1))
    const unsigned short* pa0 = Az + (size_t)(bm * 256 + (sA0 >> 3)) * Kfull + SRCOF(sA0);
    const unsigned short* pa1 = Az + (size_t)(bm * 256 + (sA1 >> 3)) * Kfull + SRCOF(sA1);
    const unsigned short* pa2 = Az + (size_t)(bm * 256 + (sA2 >> 3)) * Kfull + SRCOF(sA2);
    const unsigned short* pa3 = Az + (size_t)(bm * 256 + (sA3 >> 3)) * Kfull + SRCOF(sA3);
    const unsigned short* pb0 = Bz + (size_t)(bn * 256 + (sA0 >> 3)) * Kfull + SRCOF(sA0);
    const unsigned short* pb1 = Bz + (size_t)(bn * 256 + (sA1 >> 3)) * Kfull + SRCOF(sA1);
    const unsigned short* pb2 = Bz + (size_t)(bn * 256 + (sA2 >> 3)) * Kfull + SRCOF(sA2);
    const unsigned short* pb3 = Bz + (size_t)(bn * 256 + (sA3 >> 3)) * Kfull + SRCOF(sA3);
#undef SRCOF

#define STG(kt, bb)                                           \
    do {                                                      \
        gload_lds16(pa0 + (kt) * 64, &As[bb][sA0 * 8]);       \
        gload_lds16(pa1 + (kt) * 64, &As[bb][sA1 * 8]);       \
        gload_lds16(pa2 + (kt) * 64, &As[bb][sA2 * 8]);       \
        gload_lds16(pa3 + (kt) * 64, &As[bb][sA3 * 8]);       \
        gload_lds16(pb0 + (kt) * 64, &Bs[bb][sA0 * 8]);       \
        gload_lds16(pb1 + (kt) * 64, &Bs[bb][sA1 * 8]);       \
        gload_lds16(pb2 + (kt) * 64, &Bs[bb][sA2 * 8]);       \
        gload_lds16(pb3 + (kt) * 64, &Bs[bb][sA3 * 8]);       \
    } while (0)

    const unsigned swz = (unsigned)((l4 * 16) ^ ((l15 & 7) << 4));
    const unsigned aB0 = lds_addr(&As[0][0]) + (unsigned)((wr * 128 + l15) * 128) + swz;
    const unsigned bB0 = lds_addr(&Bs[0][0]) + (unsigned)((wc * 64 + l15) * 128) + swz;

#define DSR(dst, addr, off) \
    asm volatile("ds_read_b128 %0, %1 offset:" #off : "=v"(dst) : "v"(addr))

    STG(0, 0);
    for (int kt = 0; kt < nK; ++kt) {
        const int bc = kt & 1;
        asm volatile("s_waitcnt vmcnt(0)\ns_barrier" ::: "memory");
        __builtin_amdgcn_sched_barrier(0);

        const unsigned aA0 = aB0 + bc * 32768;
        const unsigned aA1 = aA0 ^ 64u;
        const unsigned bA0 = bB0 + bc * 32768;
        const unsigned bA1 = bA0 ^ 64u;
        bf16x8 a00, a01, a02, a03, a04, a05, a06, a07;
        bf16x8 a10, a11, a12, a13, a14, a15, a16, a17;
        bf16x8 b00, b01, b02, b03, b10, b11, b12, b13;

        // group1: B-ks0 (4) + A-ks0 m0-3 (4)
        DSR(b00, bA0, 0);    DSR(b01, bA0, 2048);
        DSR(b02, bA0, 4096); DSR(b03, bA0, 6144);
        DSR(a00, aA0, 0);    DSR(a01, aA0, 2048);
        DSR(a02, aA0, 4096); DSR(a03, aA0, 6144);
        // group2: A-ks0 m4-7 (4)
        DSR(a04, aA0, 8192);  DSR(a05, aA0, 10240);
        DSR(a06, aA0, 12288); DSR(a07, aA0, 14336);

        if (kt + 1 < nK) STG(kt + 1, bc ^ 1);

        asm volatile("s_waitcnt lgkmcnt(4)" ::: "memory");   // group1 done
        __builtin_amdgcn_sched_barrier(0);
        __builtin_amdgcn_s_setprio(1);
        acc[0][0] = MFMA16(a00, b00, acc[0][0]); acc[0][1] = MFMA16(a00, b01, acc[0][1]);
        acc[0][2] = MFMA16(a00, b02, acc[0][2]); acc[0][3] = MFMA16(a00, b03, acc[0][3]);
        acc[1][0] = MFMA16(a01, b00, acc[1][0]); acc[1][1] = MFMA16(a01, b01, acc[1][1]);
        acc[1][2] = MFMA16(a01, b02, acc[1][2]); acc[1][3] = MFMA16(a01, b03, acc[1][3]);
        acc[2][0] = MFMA16(a02, b00, acc[2][0]); acc[2][1] = MFMA16(a02, b01, acc[2][1]);
        acc[2][2] = MFMA16(a02, b02, acc[2][2]); acc[2][3] = MFMA16(a02, b03, acc[2][3]);
        acc[3][0] = MFMA16(a03, b00, acc[3][0]); acc[3][1] = MFMA16(a03, b01, acc[3][1]);
        acc[3][2] = MFMA16(a03, b02, acc[3][2]); acc[3][3] = MFMA16(a03, b03, acc[3][3]);
        __builtin_amdgcn_s_setprio(0);

        // group3: B-ks1 (4) + A-ks1 m0-3 (4)
        DSR(b10, bA1, 0);    DSR(b11, bA1, 2048);
        DSR(b12, bA1, 4096); DSR(b13, bA1, 6144);
        DSR(a10, aA1, 0);    DSR(a11, aA1, 2048);
        DSR(a12, aA1, 4096); DSR(a13, aA1, 6144);

        asm volatile("s_waitcnt lgkmcnt(8)" ::: "memory");   // group2 done
        __builtin_amdgcn_sched_barrier(0);
        __builtin_amdgcn_s_setprio(1);
        acc[4][0] = MFMA16(a04, b00, acc[4][0]); acc[4][1] = MFMA16(a04, b01, acc[4][1]);
        acc[4][2] = MFMA16(a04, b02, acc[4][2]); acc[4][3] = MFMA16(a04, b03, acc[4][3]);
        acc[5][0] = MFMA16(a05, b00, acc[5][0]); acc[5][1] = MFMA16(a05, b01, acc[5][1]);
        acc[5][2] = MFMA16(a05, b02, acc[5][2]); acc[5][3] = MFMA16(a05, b03, acc[5][3]);
        acc[6][0] = MFMA16(a06, b00, acc[6][0]); acc[6][1] = MFMA16(a06, b01, acc[6][1]);
        acc[6][2] = MFMA16(a06, b02, acc[6][2]); acc[6][3] = MFMA16(a06, b03, acc[6][3]);
        acc[7][0] = MFMA16(a07, b00, acc[7][0]); acc[7][1] = MFMA16(a07, b01, acc[7][1]);
        acc[7][2] = MFMA16(a07, b02, acc[7][2]); acc[7][3] = MFMA16(a07, b03, acc[7][3]);
        __builtin_amdgcn_s_setprio(0);

        // group4: A-ks1 m4-7 (4)
        DSR(a14, aA1, 8192);  DSR(a15, aA1, 10240);
        DSR(a16, aA1, 12288); DSR(a17, aA1, 14336);

        asm volatile("s_waitcnt lgkmcnt(4)" ::: "memory");   // group3 done
        __builtin_amdgcn_sched_barrier(0);
        __builtin_amdgcn_s_setprio(1);
        acc[0][0] = MFMA16(a10, b10, acc[0][0]); acc[0][1] = MFMA16(a10, b11, acc[0][1]);
        acc[0][2] = MFMA16(a10, b12, acc[0][2]); acc[0][3] = MFMA16(a10, b13, acc[0][3]);
        acc[1][0] = MFMA16(a11, b10, acc[1][0]); acc[1][1] = MFMA16(a11, b11, acc[1][1]);
        acc[1][2] = MFMA16(a11, b12, acc[1][2]); acc[1][3] = MFMA16(a11, b13, acc[1][3]);
        acc[2][0] = MFMA16(a12, b10, acc[2][0]); acc[2][1] = MFMA16(a12, b11, acc[2][1]);
        acc[2][2] = MFMA16(a12, b12, acc[2][2]); acc[2][3] = MFMA16(a12, b13, acc[2][3]);
        acc[3][0] = MFMA16(a13, b10, acc[3][0]); acc[3][1] = MFMA16(a13, b11, acc[3][1]);
        acc[3][2] = MFMA16(a13, b12, acc[3][2]); acc[3][3] = MFMA16(a13, b13, acc[3][3]);
        __builtin_amdgcn_s_setprio(0);

        asm volatile("s_waitcnt lgkmcnt(0)" ::: "memory");   // group4 done
        __builtin_amdgcn_sched_barrier(0);
        __builtin_amdgcn_s_setprio(1);
        acc[4][0] = MFMA16(a14, b10, acc[4][0]); acc[4][1] = MFMA16(a14, b11, acc[4][1]);
        acc[4][2] = MFMA16(a14, b12, acc[4][2]); acc[4][3] = MFMA16(a14, b13, acc[4][3]);
        acc[5][0] = MFMA16(a15, b10, acc[5][0]); acc[5][1] = MFMA16(a15, b11, acc[5][1]);
        acc[5][2] = MFMA16(a15, b12, acc[5][2]); acc[5][3] = MFMA16(a15, b13, acc[5][3]);
        acc[6][0] = MFMA16(a16, b10, acc[6][0]); acc[6][1] = MFMA16(a16, b11, acc[6][1]);
        acc[6][2] = MFMA16(a16, b12, acc[6][2]); acc[6][3] = MFMA16(a16, b13, acc[6][3]);
        acc[7][0] = MFMA16(a17, b10, acc[7][0]); acc[7][1] = MFMA16(a17, b11, acc[7][1]);
        acc[7][2] = MFMA16(a17, b12, acc[7][2]); acc[7][3] = MFMA16(a17, b13, acc[7][3]);
        __builtin_amdgcn_s_setprio(0);
    }
#undef STG
#undef DSR

    for (int m = 0; m < 8; ++m)
        for (int n = 0; n < 4; ++n)
            for (int j = 0; j < 4; ++j) {
                int row = bm * 256 + wr * 128 + m * 16 + l4 * 4 + j;
                int col = bn * 256 + wc * 64 + n * 16 + l15;
                C[(size_t)row * N + col] = f2bf_fast(acc[m][n][j]);
            }
}

// ---------------------------------------------------------------- postqkv: merged {combine+RMSNorm+RoPE (Q/K)} and {V combine+transpose}
// blocks [0, 10240): norm_rope for 20 Q/K heads; blocks [10240, 10368): V transpose
__global__ __launch_bounds__(256) void postqkv(const unsigned short* __restrict__ p0,
                                               const unsigned short* __restrict__ p1,
                                               const float* __restrict__ qw,
                                               const float* __restrict__ kw,
                                               const float2* __restrict__ tbl,
                                               unsigned short* __restrict__ Qb,
                                               unsigned short* __restrict__ Kb,
                                               unsigned short* __restrict__ VbT) {
    __shared__ unsigned short T[64 * 132];
    const int b = blockIdx.x;
    if (b < 10240) {
        // ---- norm_rope branch (uniform per block) ----
        const int row = b & 2047;
        const int head = (b >> 11) * 4 + (threadIdx.x >> 6);  // 0..19
        const int t = threadIdx.x & 63;
        const size_t off = (size_t)row * 3072 + head * 128;
        float x1 = bf2f(p0[off + t]) + bf2f(p1[off + t]);
        float x2 = bf2f(p0[off + t + 64]) + bf2f(p1[off + t + 64]);
        float ss = x1 * x1 + x2 * x2;
        for (int m = 32; m; m >>= 1) ss += __shfl_xor(ss, m);
        float r = rsqrtf(ss * (1.0f / 128.0f) + 1e-6f);
        const float* w = (head < 16) ? qw : kw;
        float y1 = x1 * r * w[t], y2 = x2 * r * w[t + 64];
        float2 cs = tbl[row * 64 + t];
        x1 = y1 * cs.x - y2 * cs.y;
        x2 = y1 * cs.y + y2 * cs.x;
        if (head < 16) {                       // fold softmax scale*log2(e) into Q
            const float SCALE2 = 0.12751879526654698f;
            x1 *= SCALE2; x2 *= SCALE2;
        }
        unsigned short* dst = (head < 16) ? Qb + ((size_t)head * 2048 + row) * 128
                                          : Kb + ((size_t)(head - 16) * 2048 + row) * 128;
        dst[t] = f2bf(x1);
        dst[t + 64] = f2bf(x2);
    } else {
        // ---- V transpose branch: VbT[h][d][kt*64+c'] = V[kt*64+k(c')][d], k(c')=(c'&3)*16+(c'>>2)
        const int idx = b - 10240;            // 0..127
        const int kt = idx & 31, h = idx >> 5;
        const int tid = threadIdx.x;
        for (int i = 0; i < 8; ++i) {
            int s = i * 256 + tid;
            int r = s >> 5, c = (s & 31) * 4;
            size_t off = (size_t)(kt * 64 + r) * 3072 + (20 + h) * 128 + c;
            ushort4 a = *(const ushort4*)(p0 + off);
            ushort4 bb = *(const ushort4*)(p1 + off);
            ushort4 o;
            o.x = f2bf(bf2f(a.x) + bf2f(bb.x));
            o.y = f2bf(bf2f(a.y) + bf2f(bb.y));
            o.z = f2bf(bf2f(a.z) + bf2f(bb.z));
            o.w = f2bf(bf2f(a.w) + bf2f(bb.w));
            *(ushort4*)&T[r * 132 + c] = o;
        }
        __syncthreads();
        for (int i = 0; i < 4; ++i) {
            int s = i * 256 + tid;
            int d = s >> 3, ck = (s & 7) * 8;
            us8 v;
            for (int j = 0; j < 8; ++j) {
                int c = ck + j;
                int k = (c & 3) * 16 + (c >> 2);
                v[j] = T[k * 132 + d];
            }
            *(us8*)(VbT + (size_t)h * 128 * 2048 + (size_t)d * 2048 + kt * 64 + ck) = v;
        }
    }
}

// ---------------------------------------------------------------- flash attention: R9 form (proven 40us)
// 2 heads/block, KVBLK=64, 8 waves; K dbuf + single-V async stage
__global__ __launch_bounds__(512) void attn_fwd(const unsigned short* __restrict__ Qb,
                                                const unsigned short* __restrict__ Kb,
                                                const unsigned short* __restrict__ VbT,
                                                unsigned short* __restrict__ Ob) {
    const int bid = blockIdx.x;
    const int p = bid & 7;           // head pair = XCD slot
    const int qt = bid >> 3;         // 0..31
    const int q0 = qt * 64;
    __shared__ unsigned short Ks[2][64 * 128];   // swizzled
    __shared__ unsigned short Vs[128 * 64];      // V^T swizzled, k-permuted columns
    __shared__ char PsB[8][16 * 136];            // packed P, stride 136B
    const int tid = threadIdx.x;
    const int lane = tid & 63, wave = tid >> 6;
    const int l15 = lane & 15, l4 = lane >> 4;
    const int h = 2 * p + (wave >> 2);           // this wave's head
    const int rgrp = wave & 3;                   // 16-row group
    const int kvh = p >> 1;

    bf16x8 qf[4];
    {
        const unsigned short* qrow =
            Qb + ((size_t)h * 2048 + q0 + rgrp * 16 + l15) * 128 + l4 * 8;
        for (int kk = 0; kk < 4; ++kk) qf[kk] = *(const bf16x8*)(qrow + kk * 32);
    }
    f32x4 o[8] = {};
    float m2[4], lp[4];
    for (int j = 0; j < 4; ++j) { m2[j] = -1e30f; lp[j] = 0.0f; }
    const int kt_lo = (qt >= 16) ? (qt - 16) : 0;

    const unsigned short* Kh = Kb + (size_t)kvh * 2048 * 128;
    const unsigned short* Vh = VbT + (size_t)kvh * 128 * 2048;

    int ksr[2], ksc[2], vsr[2], vsc[2];
    for (int i = 0; i < 2; ++i) {
        int s = i * 512 + tid;
        ksr[i] = s >> 4;
        ksc[i] = (((s & 15) * 16) ^ ((ksr[i] & 7) << 4)) >> 1;
        vsr[i] = s >> 3;
        vsc[i] = (((s & 7) * 16) ^ ((vsr[i] & 7) << 4)) >> 1;
    }

    // prologue: K[kt_lo] -> Ks[0]
    for (int i = 0; i < 2; ++i)
        gload_lds16(Kh + (size_t)(kt_lo * 64 + ksr[i]) * 128 + ksc[i],
                    &Ks[0][(i * 512 + tid) * 8]);

    int cur = 0;
    for (int kt = kt_lo; kt <= qt; ++kt) {
        asm volatile("s_waitcnt vmcnt(0)\ns_barrier" ::: "memory");
        __builtin_amdgcn_sched_barrier(0);

        // issue V[kt] (oldest), then K[kt+1]
        for (int i = 0; i < 2; ++i)
            gload_lds16(Vh + (size_t)vsr[i] * 2048 + kt * 64 + vsc[i],
                        &Vs[(i * 512 + tid) * 8]);
        if (kt < qt) {
            for (int i = 0; i < 2; ++i)
                gload_lds16(Kh + (size_t)((kt + 1) * 64 + ksr[i]) * 128 + ksc[i],
                            &Ks[cur ^ 1][(i * 512 + tid) * 8]);
        }

        // S = Q K^T (Q pre-scaled -> log2 domain)
        f32x4 s[4] = {};
        __builtin_amdgcn_s_setprio(1);
        for (int nn = 0; nn < 4; ++nn)
            for (int kk = 0; kk < 4; ++kk) {
                int r = nn * 16 + l15;
                int cb = (kk * 64 + l4 * 16) ^ ((r & 7) << 4);
                bf16x8 kf = *(const bf16x8*)((const char*)&Ks[cur][0] + r * 256 + cb);
                s[nn] = MFMA16(qf[kk], kf, s[nn]);
            }
        __builtin_amdgcn_s_setprio(0);

        float pv4[4][4];
        const bool masked = (kt == qt) || (qt >= 16 && kt == kt_lo);
        if (masked) {
            for (int nn = 0; nn < 4; ++nn) {
                int kc = kt * 64 + nn * 16 + l15;
                for (int j = 0; j < 4; ++j) {
                    int qr = q0 + rgrp * 16 + l4 * 4 + j;
                    unsigned diff = (unsigned)(qr - kc);
                    pv4[nn][j] = (diff < 1024u) ? s[nn][j] : -1e30f;
                }
            }
        } else {
            for (int nn = 0; nn < 4; ++nn)
                for (int j = 0; j < 4; ++j) pv4[nn][j] = s[nn][j];
        }

        // deferred-max: common path has NO cross-lane reduce
        float mxl[4];
        bool flag = true;
        for (int j = 0; j < 4; ++j) {
            mxl[j] = fmaxf(fmaxf(pv4[0][j], pv4[1][j]), fmaxf(pv4[2][j], pv4[3][j]));
            flag = flag && (mxl[j] <= m2[j] + 11.0f);
        }
        if (!__all(flag)) {
            for (int j = 0; j < 4; ++j) {
                float mx = mxl[j];
                for (int mk = 8; mk; mk >>= 1) mx = fmaxf(mx, __shfl_xor(mx, mk));
                float mnew = fmaxf(m2[j], mx);
                float corr = exp2f(m2[j] - mnew);
                m2[j] = mnew;
                lp[j] *= corr;
                for (int dd = 0; dd < 8; ++dd) o[dd][j] *= corr;
            }
        }
        for (int j = 0; j < 4; ++j) {
            float rs = 0.0f;
            for (int nn = 0; nn < 4; ++nn) {
                float pv = exp2f(pv4[nn][j] - m2[j]);
                pv4[nn][j] = pv;
                rs += pv;
            }
            lp[j] += rs;
        }

        // packed P store: k-permuted cols (c' = l15*4 + nn), 1 b64 write per j
        for (int j = 0; j < 4; ++j) {
            int row = l4 * 4 + j;
            unsigned lo, hi;
            asm("v_cvt_pk_bf16_f32 %0, %1, %2" : "=v"(lo) : "v"(pv4[0][j]), "v"(pv4[1][j]));
            asm("v_cvt_pk_bf16_f32 %0, %1, %2" : "=v"(hi) : "v"(pv4[2][j]), "v"(pv4[3][j]));
            int cb = (l15 * 8) ^ ((row & 7) << 4);
            *(uint2*)(&PsB[wave][0] + row * 136 + cb) = make_uint2(lo, hi);
        }

        bf16x8 pa[2];
        for (int kk2 = 0; kk2 < 2; ++kk2) {
            int cb = (kk2 * 64 + l4 * 16) ^ ((l15 & 7) << 4);
            pa[kk2] = *(const bf16x8*)(&PsB[wave][0] + l15 * 136 + cb);
        }

        // V[kt] certified (this wave's 2 V-loads are its oldest); barrier collectivizes
        if (kt < qt)
            asm volatile("s_waitcnt vmcnt(2)\ns_barrier" ::: "memory");
        else
            asm volatile("s_waitcnt vmcnt(0)\ns_barrier" ::: "memory");
        __builtin_amdgcn_sched_barrier(0);

        __builtin_amdgcn_s_setprio(1);
        for (int dd = 0; dd < 8; ++dd)
            for (int kk2 = 0; kk2 < 2; ++kk2) {
                int d = dd * 16 + l15;
                int cb = (kk2 * 64 + l4 * 16) ^ ((d & 7) << 4);
                bf16x8 vf = *(const bf16x8*)((const char*)&Vs[0] + d * 128 + cb);
                o[dd] = MFMA16(pa[kk2], vf, o[dd]);
            }
        __builtin_amdgcn_s_setprio(0);
        cur ^= 1;
    }

    for (int j = 0; j < 4; ++j) {
        float lt = lp[j];
        for (int mk = 8; mk; mk >>= 1) lt += __shfl_xor(lt, mk);
        float inv = 1.0f / lt;
        int row = q0 + rgrp * 16 + l4 * 4 + j;
        unsigned short* orow = Ob + (size_t)row * 2048 + h * 128;
        for (int dd = 0; dd < 8; ++dd) orow[dd * 16 + l15] = f2bf_fast(o[dd][j] * inv);
    }
}

// ---------------------------------------------------------------- combine 4 bf16 split-K partials -> f32 out
__global__ __launch_bounds__(256) void add4(const unsigned short* __restrict__ p,
                                            float* __restrict__ out, int n) {
    int i = (blockIdx.x * 256 + threadIdx.x) * 8;
    if (i >= n) return;
    us8 a = *(const us8*)(p + i);
    us8 b = *(const us8*)(p + 4194304 + i);
    us8 c = *(const us8*)(p + 8388608 + i);
    us8 d = *(const us8*)(p + 12582912 + i);
    f32x4 o0, o1;
    for (int j = 0; j < 4; ++j)
        o0[j] = (bf2f(a[j]) + bf2f(b[j])) + (bf2f(c[j]) + bf2f(d[j]));
    for (int j = 0; j < 4; ++j)
        o1[j] = (bf2f(a[j + 4]) + bf2f(b[j + 4])) + (bf2f(c[j + 4]) + bf2f(d[j + 4]));
    *(f32x4*)(out + i) = o0;
    *(f32x4*)(out + i + 4) = o1;
}

// ---------------------------------------------------------------- launch
extern "C" void kernel_launch(void* const* d_in, const int* in_sizes, int n_in,
                              void* d_out, int out_size, void* d_ws, size_t ws_size,
                              hipStream_t stream) {
    const float* x  = (const float*)d_in[0];
    const float* wq = (const float*)d_in[1];
    const float* wk = (const float*)d_in[2];
    const float* wv = (const float*)d_in[3];
    const float* wo = (const float*)d_in[4];
    const float* qw = (const float*)d_in[5];
    const float* kw = (const float*)d_in[6];
    float* out = (float*)d_out;

    char* ws = (char*)d_ws;
    unsigned short* xb   = (unsigned short*)(ws + 0);          //  8 MB
    unsigned short* wqkv = (unsigned short*)(ws + 8388608);    // 12 MB
    unsigned short* wob  = (unsigned short*)(ws + 20971520);   //  8 MB
    unsigned short* qkvP = (unsigned short*)(ws + 29360128);   // 25 MB bf16 x2 partials
    unsigned short* Qb   = (unsigned short*)(ws + 54525952);   //  8 MB
    unsigned short* Kb   = (unsigned short*)(ws + 62914560);   //  2 MB
    unsigned short* VbT  = (unsigned short*)(ws + 65011712);   //  2 MB
    unsigned short* Ob   = (unsigned short*)(ws + 67108864);   //  8 MB
    unsigned short* outP = (unsigned short*)(ws + 29360128);   // 32 MB bf16 x4, overlays dead qkvP/Qb
    float2*         tbl  = (float2*)(ws + 104857600);          //  1 MB

    prep_all<<<dim3(14848), dim3(256), 0, stream>>>(x, wq, wk, wv, wo, xb, wqkv, wob, tbl);
    gemm256<<<dim3(12, 8, 2), dim3(512), 0, stream>>>(xb, wqkv, qkvP, 2048, 3072, 2048, 1024);
    postqkv<<<dim3(10368), dim3(256), 0, stream>>>(qkvP, qkvP + 2048 * 3072, qw, kw, tbl, Qb, Kb, VbT);
    attn_fwd<<<dim3(256), dim3(512), 0, stream>>>(Qb, Kb, VbT, Ob);
    gemm256<<<dim3(8, 8, 4), dim3(512), 0, stream>>>(Ob, wob, outP, 2048, 2048, 2048, 512);
    add4<<<dim3(2048), dim3(256), 0, stream>>>(outP, out, 2048 * 2048);
}

// Round 22
// 121.173 us; speedup vs baseline: 1.0469x; 1.0016x over previous
//
#include <hip/hip_runtime.h>
#include <hip/hip_bf16.h>
#include <cstdint>
#include <cstddef>

typedef __attribute__((ext_vector_type(4))) float f32x4;
typedef __attribute__((ext_vector_type(8))) short bf16x8;
typedef __attribute__((ext_vector_type(8))) unsigned short us8;

#define MFMA16(a, b, c) __builtin_amdgcn_mfma_f32_16x16x32_bf16(a, b, c, 0, 0, 0)

__device__ inline unsigned short f2bf(float f) {
    unsigned int u = __float_as_uint(f);
    u += 0x7fffu + ((u >> 16) & 1u);
    return (unsigned short)(u >> 16);
}
__device__ inline float bf2f(unsigned short u) {
    return __uint_as_float((unsigned int)u << 16);
}
// 1-instruction bf16 convert (RTNE) via packed cvt
__device__ inline unsigned short f2bf_fast(float f) {
    float r;
    asm("v_cvt_pk_bf16_f32 %0, %1, %2" : "=v"(r) : "v"(f), "v"(f));
    return (unsigned short)__float_as_uint(r);
}

__device__ inline void gload_lds16(const void* g, void* l) {
    __builtin_amdgcn_global_load_lds(
        (const __attribute__((address_space(1))) void*)g,
        (__attribute__((address_space(3))) void*)l, 16, 0, 0);
}
__device__ inline unsigned lds_addr(const void* p) {
    return (unsigned)(size_t)((__attribute__((address_space(3))) const void*)p);
}

// ---------------------------------------------------------------- fused prep: 5 f32->bf16 converts + RoPE table
__global__ __launch_bounds__(256) void prep_all(const float* __restrict__ x,
                                                const float* __restrict__ wq,
                                                const float* __restrict__ wk,
                                                const float* __restrict__ wv,
                                                const float* __restrict__ wo,
                                                unsigned short* __restrict__ xb,
                                                unsigned short* __restrict__ wqkv,
                                                unsigned short* __restrict__ wob,
                                                float2* __restrict__ tbl) {
    const int b = blockIdx.x;
    if (b < 14336) {
        const float* src; unsigned short* dst; int off4;
        if (b < 4096)       { src = x;  dst = xb;                 off4 = b; }
        else if (b < 8192)  { src = wq; dst = wqkv;               off4 = b - 4096; }
        else if (b < 9216)  { src = wk; dst = wqkv + 2048 * 2048; off4 = b - 8192; }
        else if (b < 10240) { src = wv; dst = wqkv + 2560 * 2048; off4 = b - 9216; }
        else                { src = wo; dst = wob;                off4 = b - 10240; }
        int i = (off4 * 256 + threadIdx.x) * 4;
        float4 v = *(const float4*)(src + i);
        ushort4 o;
        o.x = f2bf(v.x); o.y = f2bf(v.y); o.z = f2bf(v.z); o.w = f2bf(v.w);
        *(ushort4*)(dst + i) = o;
    } else {
        int idx = (b - 14336) * 256 + threadIdx.x;
        int row = idx >> 6, t = idx & 63;
        float inv_freq = exp2f((float)t * (-2.0f / 128.0f) * 13.287712379549449f);
        float s, c;
        sincosf((float)row * inv_freq, &s, &c);
        tbl[idx] = make_float2(c, s);
    }
}

// ---------------------------------------------------------------- gemm256: BK=64, 2-buffer, 4 counted-lgkm MFMA sub-phases
__global__ __launch_bounds__(512, 1) void gemm256(const unsigned short* __restrict__ A,
                                                  const unsigned short* __restrict__ B,
                                                  unsigned short* __restrict__ Cp,
                                                  int M, int N, int Kfull, int kspan) {
    __shared__ unsigned short As[2][16384];   // 32KB each buf
    __shared__ unsigned short Bs[2][16384];
    const int tid = threadIdx.x;
    const int lane = tid & 63, wave = tid >> 6;
    const int wr = wave >> 2, wc = wave & 3;
    const int l15 = lane & 15, l4 = lane >> 4;
    const int gx = gridDim.x;
    const int nwg = gx * gridDim.y;
    const int bid0 = blockIdx.y * gx + blockIdx.x;
    const int q8 = nwg >> 3, r8 = nwg & 7;
    const int xcd = bid0 & 7, sub = bid0 >> 3;
    const int wgid = ((xcd < r8) ? xcd * (q8 + 1) : r8 * (q8 + 1) + (xcd - r8) * q8) + sub;
    const int bm = wgid / gx, bn = wgid % gx;
    const int z = blockIdx.z;
    const unsigned short* Az = A + (size_t)z * kspan;
    const unsigned short* Bz = B + (size_t)z * kspan;
    unsigned short* C = Cp + (size_t)z * M * N;
    const int nK = kspan >> 6;   // BK=64

    f32x4 acc[8][4] = {};

    const int sA0 = tid, sA1 = 512 + tid, sA2 = 1024 + tid, sA3 = 1536 + tid;
#define SRCOF(s) ((((((s) & 7) * 16) ^ ((((s) >> 3) & 7) << 4)) >> 1))
    const unsigned short* pa0 = Az + (size_t)(bm * 256 + (sA0 >> 3)) * Kfull + SRCOF(sA0);
    const unsigned short* pa1 = Az + (size_t)(bm * 256 + (sA1 >> 3)) * Kfull + SRCOF(sA1);
    const unsigned short* pa2 = Az + (size_t)(bm * 256 + (sA2 >> 3)) * Kfull + SRCOF(sA2);
    const unsigned short* pa3 = Az + (size_t)(bm * 256 + (sA3 >> 3)) * Kfull + SRCOF(sA3);
    const unsigned short* pb0 = Bz + (size_t)(bn * 256 + (sA0 >> 3)) * Kfull + SRCOF(sA0);
    const unsigned short* pb1 = Bz + (size_t)(bn * 256 + (sA1 >> 3)) * Kfull + SRCOF(sA1);
    const unsigned short* pb2 = Bz + (size_t)(bn * 256 + (sA2 >> 3)) * Kfull + SRCOF(sA2);
    const unsigned short* pb3 = Bz + (size_t)(bn * 256 + (sA3 >> 3)) * Kfull + SRCOF(sA3);
#undef SRCOF

#define STG(kt, bb)                                           \
    do {                                                      \
        gload_lds16(pa0 + (kt) * 64, &As[bb][sA0 * 8]);       \
        gload_lds16(pa1 + (kt) * 64, &As[bb][sA1 * 8]);       \
        gload_lds16(pa2 + (kt) * 64, &As[bb][sA2 * 8]);       \
        gload_lds16(pa3 + (kt) * 64, &As[bb][sA3 * 8]);       \
        gload_lds16(pb0 + (kt) * 64, &Bs[bb][sA0 * 8]);       \
        gload_lds16(pb1 + (kt) * 64, &Bs[bb][sA1 * 8]);       \
        gload_lds16(pb2 + (kt) * 64, &Bs[bb][sA2 * 8]);       \
        gload_lds16(pb3 + (kt) * 64, &Bs[bb][sA3 * 8]);       \
    } while (0)

    const unsigned swz = (unsigned)((l4 * 16) ^ ((l15 & 7) << 4));
    const unsigned aB0 = lds_addr(&As[0][0]) + (unsigned)((wr * 128 + l15) * 128) + swz;
    const unsigned bB0 = lds_addr(&Bs[0][0]) + (unsigned)((wc * 64 + l15) * 128) + swz;

#define DSR(dst, addr, off) \
    asm volatile("ds_read_b128 %0, %1 offset:" #off : "=v"(dst) : "v"(addr))

    STG(0, 0);
    for (int kt = 0; kt < nK; ++kt) {
        const int bc = kt & 1;
        asm volatile("s_waitcnt vmcnt(0)\ns_barrier" ::: "memory");
        __builtin_amdgcn_sched_barrier(0);

        const unsigned aA0 = aB0 + bc * 32768;
        const unsigned aA1 = aA0 ^ 64u;
        const unsigned bA0 = bB0 + bc * 32768;
        const unsigned bA1 = bA0 ^ 64u;
        bf16x8 a00, a01, a02, a03, a04, a05, a06, a07;
        bf16x8 a10, a11, a12, a13, a14, a15, a16, a17;
        bf16x8 b00, b01, b02, b03, b10, b11, b12, b13;

        // group1: B-ks0 (4) + A-ks0 m0-3 (4)
        DSR(b00, bA0, 0);    DSR(b01, bA0, 2048);
        DSR(b02, bA0, 4096); DSR(b03, bA0, 6144);
        DSR(a00, aA0, 0);    DSR(a01, aA0, 2048);
        DSR(a02, aA0, 4096); DSR(a03, aA0, 6144);
        // group2: A-ks0 m4-7 (4)
        DSR(a04, aA0, 8192);  DSR(a05, aA0, 10240);
        DSR(a06, aA0, 12288); DSR(a07, aA0, 14336);

        if (kt + 1 < nK) STG(kt + 1, bc ^ 1);

        asm volatile("s_waitcnt lgkmcnt(4)" ::: "memory");   // group1 done
        __builtin_amdgcn_sched_barrier(0);
        __builtin_amdgcn_s_setprio(1);
        acc[0][0] = MFMA16(a00, b00, acc[0][0]); acc[0][1] = MFMA16(a00, b01, acc[0][1]);
        acc[0][2] = MFMA16(a00, b02, acc[0][2]); acc[0][3] = MFMA16(a00, b03, acc[0][3]);
        acc[1][0] = MFMA16(a01, b00, acc[1][0]); acc[1][1] = MFMA16(a01, b01, acc[1][1]);
        acc[1][2] = MFMA16(a01, b02, acc[1][2]); acc[1][3] = MFMA16(a01, b03, acc[1][3]);
        acc[2][0] = MFMA16(a02, b00, acc[2][0]); acc[2][1] = MFMA16(a02, b01, acc[2][1]);
        acc[2][2] = MFMA16(a02, b02, acc[2][2]); acc[2][3] = MFMA16(a02, b03, acc[2][3]);
        acc[3][0] = MFMA16(a03, b00, acc[3][0]); acc[3][1] = MFMA16(a03, b01, acc[3][1]);
        acc[3][2] = MFMA16(a03, b02, acc[3][2]); acc[3][3] = MFMA16(a03, b03, acc[3][3]);
        __builtin_amdgcn_s_setprio(0);

        // group3: B-ks1 (4) + A-ks1 m0-3 (4)
        DSR(b10, bA1, 0);    DSR(b11, bA1, 2048);
        DSR(b12, bA1, 4096); DSR(b13, bA1, 6144);
        DSR(a10, aA1, 0);    DSR(a11, aA1, 2048);
        DSR(a12, aA1, 4096); DSR(a13, aA1, 6144);

        asm volatile("s_waitcnt lgkmcnt(8)" ::: "memory");   // group2 done
        __builtin_amdgcn_sched_barrier(0);
        __builtin_amdgcn_s_setprio(1);
        acc[4][0] = MFMA16(a04, b00, acc[4][0]); acc[4][1] = MFMA16(a04, b01, acc[4][1]);
        acc[4][2] = MFMA16(a04, b02, acc[4][2]); acc[4][3] = MFMA16(a04, b03, acc[4][3]);
        acc[5][0] = MFMA16(a05, b00, acc[5][0]); acc[5][1] = MFMA16(a05, b01, acc[5][1]);
        acc[5][2] = MFMA16(a05, b02, acc[5][2]); acc[5][3] = MFMA16(a05, b03, acc[5][3]);
        acc[6][0] = MFMA16(a06, b00, acc[6][0]); acc[6][1] = MFMA16(a06, b01, acc[6][1]);
        acc[6][2] = MFMA16(a06, b02, acc[6][2]); acc[6][3] = MFMA16(a06, b03, acc[6][3]);
        acc[7][0] = MFMA16(a07, b00, acc[7][0]); acc[7][1] = MFMA16(a07, b01, acc[7][1]);
        acc[7][2] = MFMA16(a07, b02, acc[7][2]); acc[7][3] = MFMA16(a07, b03, acc[7][3]);
        __builtin_amdgcn_s_setprio(0);

        // group4: A-ks1 m4-7 (4)
        DSR(a14, aA1, 8192);  DSR(a15, aA1, 10240);
        DSR(a16, aA1, 12288); DSR(a17, aA1, 14336);

        asm volatile("s_waitcnt lgkmcnt(4)" ::: "memory");   // group3 done
        __builtin_amdgcn_sched_barrier(0);
        __builtin_amdgcn_s_setprio(1);
        acc[0][0] = MFMA16(a10, b10, acc[0][0]); acc[0][1] = MFMA16(a10, b11, acc[0][1]);
        acc[0][2] = MFMA16(a10, b12, acc[0][2]); acc[0][3] = MFMA16(a10, b13, acc[0][3]);
        acc[1][0] = MFMA16(a11, b10, acc[1][0]); acc[1][1] = MFMA16(a11, b11, acc[1][1]);
        acc[1][2] = MFMA16(a11, b12, acc[1][2]); acc[1][3] = MFMA16(a11, b13, acc[1][3]);
        acc[2][0] = MFMA16(a12, b10, acc[2][0]); acc[2][1] = MFMA16(a12, b11, acc[2][1]);
        acc[2][2] = MFMA16(a12, b12, acc[2][2]); acc[2][3] = MFMA16(a12, b13, acc[2][3]);
        acc[3][0] = MFMA16(a13, b10, acc[3][0]); acc[3][1] = MFMA16(a13, b11, acc[3][1]);
        acc[3][2] = MFMA16(a13, b12, acc[3][2]); acc[3][3] = MFMA16(a13, b13, acc[3][3]);
        __builtin_amdgcn_s_setprio(0);

        asm volatile("s_waitcnt lgkmcnt(0)" ::: "memory");   // group4 done
        __builtin_amdgcn_sched_barrier(0);
        __builtin_amdgcn_s_setprio(1);
        acc[4][0] = MFMA16(a14, b10, acc[4][0]); acc[4][1] = MFMA16(a14, b11, acc[4][1]);
        acc[4][2] = MFMA16(a14, b12, acc[4][2]); acc[4][3] = MFMA16(a14, b13, acc[4][3]);
        acc[5][0] = MFMA16(a15, b10, acc[5][0]); acc[5][1] = MFMA16(a15, b11, acc[5][1]);
        acc[5][2] = MFMA16(a15, b12, acc[5][2]); acc[5][3] = MFMA16(a15, b13, acc[5][3]);
        acc[6][0] = MFMA16(a16, b10, acc[6][0]); acc[6][1] = MFMA16(a16, b11, acc[6][1]);
        acc[6][2] = MFMA16(a16, b12, acc[6][2]); acc[6][3] = MFMA16(a16, b13, acc[6][3]);
        acc[7][0] = MFMA16(a17, b10, acc[7][0]); acc[7][1] = MFMA16(a17, b11, acc[7][1]);
        acc[7][2] = MFMA16(a17, b12, acc[7][2]); acc[7][3] = MFMA16(a17, b13, acc[7][3]);
        __builtin_amdgcn_s_setprio(0);
    }
#undef STG
#undef DSR

    for (int m = 0; m < 8; ++m)
        for (int n = 0; n < 4; ++n)
            for (int j = 0; j < 4; ++j) {
                int row = bm * 256 + wr * 128 + m * 16 + l4 * 4 + j;
                int col = bn * 256 + wc * 64 + n * 16 + l15;
                C[(size_t)row * N + col] = f2bf_fast(acc[m][n][j]);
            }
}

// ---------------------------------------------------------------- postqkv: merged {combine+RMSNorm+RoPE (Q/K)} and {V combine+transpose}
// blocks [0, 10240): norm_rope for 20 Q/K heads; blocks [10240, 10368): V transpose
__global__ __launch_bounds__(256) void postqkv(const unsigned short* __restrict__ p0,
                                               const unsigned short* __restrict__ p1,
                                               const float* __restrict__ qw,
                                               const float* __restrict__ kw,
                                               const float2* __restrict__ tbl,
                                               unsigned short* __restrict__ Qb,
                                               unsigned short* __restrict__ Kb,
                                               unsigned short* __restrict__ VbT) {
    __shared__ unsigned short T[64 * 132];
    const int b = blockIdx.x;
    if (b < 10240) {
        // ---- norm_rope branch (uniform per block) ----
        const int row = b & 2047;
        const int head = (b >> 11) * 4 + (threadIdx.x >> 6);  // 0..19
        const int t = threadIdx.x & 63;
        const size_t off = (size_t)row * 3072 + head * 128;
        float x1 = bf2f(p0[off + t]) + bf2f(p1[off + t]);
        float x2 = bf2f(p0[off + t + 64]) + bf2f(p1[off + t + 64]);
        float ss = x1 * x1 + x2 * x2;
        for (int m = 32; m; m >>= 1) ss += __shfl_xor(ss, m);
        float r = rsqrtf(ss * (1.0f / 128.0f) + 1e-6f);
        const float* w = (head < 16) ? qw : kw;
        float y1 = x1 * r * w[t], y2 = x2 * r * w[t + 64];
        float2 cs = tbl[row * 64 + t];
        x1 = y1 * cs.x - y2 * cs.y;
        x2 = y1 * cs.y + y2 * cs.x;
        if (head < 16) {                       // fold softmax scale*log2(e) into Q
            const float SCALE2 = 0.12751879526654698f;
            x1 *= SCALE2; x2 *= SCALE2;
        }
        unsigned short* dst = (head < 16) ? Qb + ((size_t)head * 2048 + row) * 128
                                          : Kb + ((size_t)(head - 16) * 2048 + row) * 128;
        dst[t] = f2bf(x1);
        dst[t + 64] = f2bf(x2);
    } else {
        // ---- V transpose branch: VbT[h][d][kt*64+c'] = V[kt*64+k(c')][d], k(c')=(c'&3)*16+(c'>>2)
        const int idx = b - 10240;            // 0..127
        const int kt = idx & 31, h = idx >> 5;
        const int tid = threadIdx.x;
        for (int i = 0; i < 8; ++i) {
            int s = i * 256 + tid;
            int r = s >> 5, c = (s & 31) * 4;
            size_t off = (size_t)(kt * 64 + r) * 3072 + (20 + h) * 128 + c;
            ushort4 a = *(const ushort4*)(p0 + off);
            ushort4 bb = *(const ushort4*)(p1 + off);
            ushort4 o;
            o.x = f2bf(bf2f(a.x) + bf2f(bb.x));
            o.y = f2bf(bf2f(a.y) + bf2f(bb.y));
            o.z = f2bf(bf2f(a.z) + bf2f(bb.z));
            o.w = f2bf(bf2f(a.w) + bf2f(bb.w));
            *(ushort4*)&T[r * 132 + c] = o;
        }
        __syncthreads();
        for (int i = 0; i < 4; ++i) {
            int s = i * 256 + tid;
            int d = s >> 3, ck = (s & 7) * 8;
            us8 v;
            for (int j = 0; j < 8; ++j) {
                int c = ck + j;
                int k = (c & 3) * 16 + (c >> 2);
                v[j] = T[k * 132 + d];
            }
            *(us8*)(VbT + (size_t)h * 128 * 2048 + (size_t)d * 2048 + kt * 64 + ck) = v;
        }
    }
}

// ---------------------------------------------------------------- flash attention: R9 form (proven 40us)
// 2 heads/block, KVBLK=64, 8 waves; K dbuf + single-V async stage
__global__ __launch_bounds__(512) void attn_fwd(const unsigned short* __restrict__ Qb,
                                                const unsigned short* __restrict__ Kb,
                                                const unsigned short* __restrict__ VbT,
                                                unsigned short* __restrict__ Ob) {
    const int bid = blockIdx.x;
    const int p = bid & 7;           // head pair = XCD slot
    const int qt = bid >> 3;         // 0..31
    const int q0 = qt * 64;
    __shared__ unsigned short Ks[2][64 * 128];   // swizzled
    __shared__ unsigned short Vs[128 * 64];      // V^T swizzled, k-permuted columns
    __shared__ char PsB[8][16 * 136];            // packed P, stride 136B
    const int tid = threadIdx.x;
    const int lane = tid & 63, wave = tid >> 6;
    const int l15 = lane & 15, l4 = lane >> 4;
    const int h = 2 * p + (wave >> 2);           // this wave's head
    const int rgrp = wave & 3;                   // 16-row group
    const int kvh = p >> 1;

    bf16x8 qf[4];
    {
        const unsigned short* qrow =
            Qb + ((size_t)h * 2048 + q0 + rgrp * 16 + l15) * 128 + l4 * 8;
        for (int kk = 0; kk < 4; ++kk) qf[kk] = *(const bf16x8*)(qrow + kk * 32);
    }
    f32x4 o[8] = {};
    float m2[4], lp[4];
    for (int j = 0; j < 4; ++j) { m2[j] = -1e30f; lp[j] = 0.0f; }
    const int kt_lo = (qt >= 16) ? (qt - 16) : 0;

    const unsigned short* Kh = Kb + (size_t)kvh * 2048 * 128;
    const unsigned short* Vh = VbT + (size_t)kvh * 128 * 2048;

    int ksr[2], ksc[2], vsr[2], vsc[2];
    for (int i = 0; i < 2; ++i) {
        int s = i * 512 + tid;
        ksr[i] = s >> 4;
        ksc[i] = (((s & 15) * 16) ^ ((ksr[i] & 7) << 4)) >> 1;
        vsr[i] = s >> 3;
        vsc[i] = (((s & 7) * 16) ^ ((vsr[i] & 7) << 4)) >> 1;
    }

    // prologue: K[kt_lo] -> Ks[0]
    for (int i = 0; i < 2; ++i)
        gload_lds16(Kh + (size_t)(kt_lo * 64 + ksr[i]) * 128 + ksc[i],
                    &Ks[0][(i * 512 + tid) * 8]);

    int cur = 0;
    for (int kt = kt_lo; kt <= qt; ++kt) {
        asm volatile("s_waitcnt vmcnt(0)\ns_barrier" ::: "memory");
        __builtin_amdgcn_sched_barrier(0);

        // issue V[kt] (oldest), then K[kt+1]
        for (int i = 0; i < 2; ++i)
            gload_lds16(Vh + (size_t)vsr[i] * 2048 + kt * 64 + vsc[i],
                        &Vs[(i * 512 + tid) * 8]);
        if (kt < qt) {
            for (int i = 0; i < 2; ++i)
                gload_lds16(Kh + (size_t)((kt + 1) * 64 + ksr[i]) * 128 + ksc[i],
                            &Ks[cur ^ 1][(i * 512 + tid) * 8]);
        }

        // S = Q K^T (Q pre-scaled -> log2 domain)
        f32x4 s[4] = {};
        __builtin_amdgcn_s_setprio(1);
        for (int nn = 0; nn < 4; ++nn)
            for (int kk = 0; kk < 4; ++kk) {
                int r = nn * 16 + l15;
                int cb = (kk * 64 + l4 * 16) ^ ((r & 7) << 4);
                bf16x8 kf = *(const bf16x8*)((const char*)&Ks[cur][0] + r * 256 + cb);
                s[nn] = MFMA16(qf[kk], kf, s[nn]);
            }
        __builtin_amdgcn_s_setprio(0);

        float pv4[4][4];
        const bool masked = (kt == qt) || (qt >= 16 && kt == kt_lo);
        if (masked) {
            for (int nn = 0; nn < 4; ++nn) {
                int kc = kt * 64 + nn * 16 + l15;
                for (int j = 0; j < 4; ++j) {
                    int qr = q0 + rgrp * 16 + l4 * 4 + j;
                    unsigned diff = (unsigned)(qr - kc);
                    pv4[nn][j] = (diff < 1024u) ? s[nn][j] : -1e30f;
                }
            }
        } else {
            for (int nn = 0; nn < 4; ++nn)
                for (int j = 0; j < 4; ++j) pv4[nn][j] = s[nn][j];
        }

        // deferred-max: common path has NO cross-lane reduce
        float mxl[4];
        bool flag = true;
        for (int j = 0; j < 4; ++j) {
            mxl[j] = fmaxf(fmaxf(pv4[0][j], pv4[1][j]), fmaxf(pv4[2][j], pv4[3][j]));
            flag = flag && (mxl[j] <= m2[j] + 11.0f);
        }
        if (!__all(flag)) {
            for (int j = 0; j < 4; ++j) {
                float mx = mxl[j];
                for (int mk = 8; mk; mk >>= 1) mx = fmaxf(mx, __shfl_xor(mx, mk));
                float mnew = fmaxf(m2[j], mx);
                float corr = exp2f(m2[j] - mnew);
                m2[j] = mnew;
                lp[j] *= corr;
                for (int dd = 0; dd < 8; ++dd) o[dd][j] *= corr;
            }
        }
        for (int j = 0; j < 4; ++j) {
            float rs = 0.0f;
            for (int nn = 0; nn < 4; ++nn) {
                float pv = exp2f(pv4[nn][j] - m2[j]);
                pv4[nn][j] = pv;
                rs += pv;
            }
            lp[j] += rs;
        }

        // packed P store: k-permuted cols (c' = l15*4 + nn), 1 b64 write per j
        for (int j = 0; j < 4; ++j) {
            int row = l4 * 4 + j;
            unsigned lo, hi;
            asm("v_cvt_pk_bf16_f32 %0, %1, %2" : "=v"(lo) : "v"(pv4[0][j]), "v"(pv4[1][j]));
            asm("v_cvt_pk_bf16_f32 %0, %1, %2" : "=v"(hi) : "v"(pv4[2][j]), "v"(pv4[3][j]));
            int cb = (l15 * 8) ^ ((row & 7) << 4);
            *(uint2*)(&PsB[wave][0] + row * 136 + cb) = make_uint2(lo, hi);
        }

        bf16x8 pa[2];
        for (int kk2 = 0; kk2 < 2; ++kk2) {
            int cb = (kk2 * 64 + l4 * 16) ^ ((l15 & 7) << 4);
            pa[kk2] = *(const bf16x8*)(&PsB[wave][0] + l15 * 136 + cb);
        }

        // V[kt] certified (this wave's 2 V-loads are its oldest); barrier collectivizes
        if (kt < qt)
            asm volatile("s_waitcnt vmcnt(2)\ns_barrier" ::: "memory");
        else
            asm volatile("s_waitcnt vmcnt(0)\ns_barrier" ::: "memory");
        __builtin_amdgcn_sched_barrier(0);

        __builtin_amdgcn_s_setprio(1);
        for (int dd = 0; dd < 8; ++dd)
            for (int kk2 = 0; kk2 < 2; ++kk2) {
                int d = dd * 16 + l15;
                int cb = (kk2 * 64 + l4 * 16) ^ ((d & 7) << 4);
                bf16x8 vf = *(const bf16x8*)((const char*)&Vs[0] + d * 128 + cb);
                o[dd] = MFMA16(pa[kk2], vf, o[dd]);
            }
        __builtin_amdgcn_s_setprio(0);
        cur ^= 1;
    }

    for (int j = 0; j < 4; ++j) {
        float lt = lp[j];
        for (int mk = 8; mk; mk >>= 1) lt += __shfl_xor(lt, mk);
        float inv = 1.0f / lt;
        int row = q0 + rgrp * 16 + l4 * 4 + j;
        unsigned short* orow = Ob + (size_t)row * 2048 + h * 128;
        for (int dd = 0; dd < 8; ++dd) orow[dd * 16 + l15] = f2bf_fast(o[dd][j] * inv);
    }
}

// ---------------------------------------------------------------- combine 4 bf16 split-K partials -> f32 out
__global__ __launch_bounds__(256) void add4(const unsigned short* __restrict__ p,
                                            float* __restrict__ out, int n) {
    int i = (blockIdx.x * 256 + threadIdx.x) * 8;
    if (i >= n) return;
    us8 a = *(const us8*)(p + i);
    us8 b = *(const us8*)(p + 4194304 + i);
    us8 c = *(const us8*)(p + 8388608 + i);
    us8 d = *(const us8*)(p + 12582912 + i);
    f32x4 o0, o1;
    for (int j = 0; j < 4; ++j)
        o0[j] = (bf2f(a[j]) + bf2f(b[j])) + (bf2f(c[j]) + bf2f(d[j]));
    for (int j = 0; j < 4; ++j)
        o1[j] = (bf2f(a[j + 4]) + bf2f(b[j + 4])) + (bf2f(c[j + 4]) + bf2f(d[j + 4]));
    *(f32x4*)(out + i) = o0;
    *(f32x4*)(out + i + 4) = o1;
}

// ---------------------------------------------------------------- launch
extern "C" void kernel_launch(void* const* d_in, const int* in_sizes, int n_in,
                              void* d_out, int out_size, void* d_ws, size_t ws_size,
                              hipStream_t stream) {
    const float* x  = (const float*)d_in[0];
    const float* wq = (const float*)d_in[1];
    const float* wk = (const float*)d_in[2];
    const float* wv = (const float*)d_in[3];
    const float* wo = (const float*)d_in[4];
    const float* qw = (const float*)d_in[5];
    const float* kw = (const float*)d_in[6];
    float* out = (float*)d_out;

    char* ws = (char*)d_ws;
    unsigned short* xb   = (unsigned short*)(ws + 0);          //  8 MB
    unsigned short* wqkv = (unsigned short*)(ws + 8388608);    // 12 MB
    unsigned short* wob  = (unsigned short*)(ws + 20971520);   //  8 MB
    unsigned short* qkvP = (unsigned short*)(ws + 29360128);   // 25 MB bf16 x2 partials
    unsigned short* Qb   = (unsigned short*)(ws + 54525952);   //  8 MB
    unsigned short* Kb   = (unsigned short*)(ws + 62914560);   //  2 MB
    unsigned short* VbT  = (unsigned short*)(ws + 65011712);   //  2 MB
    unsigned short* Ob   = (unsigned short*)(ws + 67108864);   //  8 MB
    unsigned short* outP = (unsigned short*)(ws + 29360128);   // 32 MB bf16 x4, overlays dead qkvP/Qb
    float2*         tbl  = (float2*)(ws + 104857600);          //  1 MB

    prep_all<<<dim3(14848), dim3(256), 0, stream>>>(x, wq, wk, wv, wo, xb, wqkv, wob, tbl);
    gemm256<<<dim3(12, 8, 2), dim3(512), 0, stream>>>(xb, wqkv, qkvP, 2048, 3072, 2048, 1024);
    postqkv<<<dim3(10368), dim3(256), 0, stream>>>(qkvP, qkvP + 2048 * 3072, qw, kw, tbl, Qb, Kb, VbT);
    attn_fwd<<<dim3(256), dim3(512), 0, stream>>>(Qb, Kb, VbT, Ob);
    gemm256<<<dim3(8, 8, 4), dim3(512), 0, stream>>>(Ob, wob, outP, 2048, 2048, 2048, 512);
    add4<<<dim3(2048), dim3(256), 0, stream>>>(outP, out, 2048 * 2048);
}